// Round 1
// baseline (1482.367 us; speedup 1.0000x reference)
//
#include <hip/hip_runtime.h>
#include <cstdio>
#include <cstdint>

#define CCH 64      // channels C
#define EMBD 32     // embedding dim
#define NBD 8       // num radial basis
#define RHD 32      // radial hidden
#define NATTR 100   // distinct node_attr values

static constexpr float MAXR    = 2.5f;
static constexpr float INVNN   = 0.17677669529663687f;  // 1/sqrt(32)
static constexpr float EFK     = 2.5298221281347035f;   // sqrt(2/2.5)*sqrt(8)
static constexpr float SQRT3   = 1.7320508075688772f;
static constexpr float PI_F    = 3.14159265358979323846f;

__device__ __forceinline__ float sigm_(float x) { return 1.f / (1.f + __expf(-x)); }
__device__ __forceinline__ float silu_(float x) { return x / (1.f + __expf(-x)); }

// ---------------- Q = polar factor of uplift_M (64x2) ----------------
__global__ void kQ(const float* M, float* Q) {
    int c = threadIdx.x;  // 64 threads = 1 wave
    float m0 = M[2*c], m1 = M[2*c+1];
    float a = m0*m0, b = m0*m1, d = m1*m1;
    for (int o = 32; o > 0; o >>= 1) {
        a += __shfl_xor(a, o); b += __shfl_xor(b, o); d += __shfl_xor(d, o);
    }
    float det = a*d - b*b;
    float s = sqrtf(det);
    float t = sqrtf(a + d + 2.f*s);
    float inv = 1.f / (s*t);
    float i00 = (d + s)*inv, i01 = -b*inv, i11 = (a + s)*inv;
    Q[2*c]   = m0*i00 + m1*i01;
    Q[2*c+1] = m0*i01 + m1*i11;
}

// ---------------- init y, xcur ----------------
__global__ void kInit(const float* x, const float* Q, float* yAs, float* yAv,
                      float* xcur, int n) {
    int tid = blockIdx.x*blockDim.x + threadIdx.x;
    int node = tid >> 6, c = tid & 63;
    if (node >= n) return;
    const float* xr = x + (size_t)node*6;
    float q0 = Q[2*c], q1 = Q[2*c+1];
    float* yv = yAv + (size_t)node*192 + c*3;
    yv[0] = q0*xr[0] + q1*xr[3];
    yv[1] = q0*xr[1] + q1*xr[4];
    yv[2] = q0*xr[2] + q1*xr[5];
    yAs[(size_t)node*64 + c] = 0.f;
    if (c < 6) xcur[(size_t)node*6 + c] = xr[c];
}

// ---------------- CSR build ----------------
__global__ void kHist(const int* dst, int* cnt, int e) {
    int i = blockIdx.x*blockDim.x + threadIdx.x;
    if (i < e) atomicAdd(&cnt[dst[i]], 1);
}

__global__ void kScan(const int* cnt, int* offs, int* cursor, int n) {
    __shared__ int part[1024];
    int t = threadIdx.x;
    int chunk = (n + 1023) >> 10;
    int lo = t*chunk, hi = min(lo + chunk, n);
    int s = 0;
    for (int i = lo; i < hi; ++i) s += cnt[i];
    part[t] = s;
    __syncthreads();
    for (int o = 1; o < 1024; o <<= 1) {
        int w = (t >= o) ? part[t - o] : 0;
        __syncthreads();
        part[t] += w;
        __syncthreads();
    }
    int run = part[t] - s;  // exclusive prefix of this thread's chunk
    for (int i = lo; i < hi; ++i) {
        int cv = cnt[i];
        offs[i] = run; cursor[i] = run;
        run += cv;
    }
    if (t == 1023) offs[n] = part[1023];
}

__global__ void kScatter(const int* src, const int* dst, int* cursor,
                         int* srcSorted, int e) {
    int i = blockIdx.x*blockDim.x + threadIdx.x;
    if (i < e) {
        int p = atomicAdd(&cursor[dst[i]], 1);
        srcSorted[p] = src[i];
    }
}

// ---------------- T tables: contract emb_table into sc weights ----------------
// Ts[l][a][c][o] = sum_e embT[a][e]*sc_s_w[l][c][e][o]  (o<128)
// Tv[l][a][c][o] = sum_e embT[a][e]*sc_v_w[l][c][e][o]  (o<64)
__global__ void kT(const float* embT, const float* scs, const float* scv,
                   float* Ts, float* Tv) {
    int c = blockIdx.x, a = blockIdx.y, l = blockIdx.z;
    int t = threadIdx.x;  // 192 threads
    const float* e = embT + a*EMBD;
    if (t < 128) {
        const float* w = scs + ((size_t)(l*CCH + c)*EMBD)*128 + t;
        float acc = 0.f;
        #pragma unroll
        for (int k = 0; k < EMBD; ++k) acc += e[k]*w[(size_t)k*128];
        Ts[(((size_t)l*NATTR + a)*CCH + c)*128 + t] = acc;
    } else {
        int o = t - 128;
        const float* w = scv + ((size_t)(l*CCH + c)*EMBD)*64 + o;
        float acc = 0.f;
        #pragma unroll
        for (int k = 0; k < EMBD; ++k) acc += e[k]*w[(size_t)k*64];
        Tv[(((size_t)l*NATTR + a)*CCH + c)*64 + o] = acc;
    }
}

// ---------------- lin1: s1 = ys@L1s ; v1 = yv . L1v ----------------
__global__ __launch_bounds__(256) void kLin1(const float* ys, const float* yv,
        const float* L1s, const float* L1v, float* s1, float* v1, int n) {
    __shared__ float sLs[64*64], sLv[64*64];
    int t = threadIdx.x;
    for (int i = t; i < 4096; i += 256) { sLs[i] = L1s[i]; sLv[i] = L1v[i]; }
    __syncthreads();
    int lane = t & 63;
    int node = blockIdx.x*4 + (t >> 6);
    if (node >= n) return;
    float ys_r = ys[(size_t)node*64 + lane];
    const float* yvp = yv + (size_t)node*192 + lane*3;
    float y0 = yvp[0], y1 = yvp[1], y2 = yvp[2];
    float as = 0.f, a0 = 0.f, a1 = 0.f, a2 = 0.f;
    #pragma unroll 8
    for (int c = 0; c < 64; ++c) {
        float ysc = __shfl(ys_r, c);
        float b0 = __shfl(y0, c), b1 = __shfl(y1, c), b2 = __shfl(y2, c);
        float ws = sLs[c*64 + lane], wv = sLv[c*64 + lane];
        as = fmaf(ysc, ws, as);
        a0 = fmaf(b0, wv, a0); a1 = fmaf(b1, wv, a1); a2 = fmaf(b2, wv, a2);
    }
    s1[(size_t)node*64 + lane] = as;
    float* vp = v1 + (size_t)node*192 + lane*3;
    vp[0] = a0; vp[1] = a1; vp[2] = a2;
}

// ---------------- aggregation: wave per dst node, lane = channel ----------------
__global__ __launch_bounds__(256) void kAgg(const float* xcur, const float* s1,
        const float* v1, const int* offs, const int* srcSorted,
        const float* rW1, const float* rb1, const float* rW2,
        float* aggS, float* aggV, int n, int withV) {
    __shared__ float sW1[NBD*RHD];
    __shared__ float sB1[RHD];
    __shared__ float sW2[RHD*128];
    int t = threadIdx.x;
    for (int i = t; i < NBD*RHD; i += 256) sW1[i] = rW1[i];
    if (t < RHD) sB1[t] = rb1[t];
    for (int i = t; i < RHD*128; i += 256) sW2[i] = rW2[i];
    __syncthreads();
    int lane = t & 63;
    int node = blockIdx.x*4 + (t >> 6);
    if (node >= n) return;
    float px = xcur[(size_t)node*6+0], py = xcur[(size_t)node*6+1], pz = xcur[(size_t)node*6+2];
    int beg = offs[node], end = offs[node+1];
    float accS = 0.f, av0 = 0.f, av1 = 0.f, av2 = 0.f;
    for (int idx = beg; idx < end; ++idx) {
        int src = srcSorted[idx];
        const float* sp = xcur + (size_t)src*6;
        float ex = sp[0]-px, ey = sp[1]-py, ez = sp[2]-pz;
        float elen = sqrtf(ex*ex + ey*ey + ez*ez);
        if (elen >= MAXR) continue;           // cut == 0 -> zero messages (wave-uniform)
        float safe = fmaxf(elen, 1e-9f);
        float invSafe = 1.f/safe;
        float th = PI_F * safe * (1.f/MAXR);
        float s0, c0;
        __sincosf(th, &s0, &c0);
        float ef[NBD];
        float sPrev = 0.f, sCur = s0, twoC = 2.f*c0;
        #pragma unroll
        for (int b = 0; b < NBD; ++b) {       // ef[b] ~ sin((b+1)th)
            ef[b] = EFK * sCur * invSafe;
            float sN = twoC*sCur - sPrev;
            sPrev = sCur; sCur = sN;
        }
        // hidden units on lanes 0..31
        float hid = 0.f;
        if (lane < RHD) {
            hid = sB1[lane];
            #pragma unroll
            for (int b = 0; b < NBD; ++b) hid = fmaf(ef[b], sW1[b*RHD + lane], hid);
            hid = silu_(hid);
        }
        float w1 = 0.f, w2 = 0.f;
        #pragma unroll
        for (int r = 0; r < RHD; ++r) {
            float hv = __shfl(hid, r);
            if (withV) w1 = fmaf(hv, sW2[r*128 + lane], w1);
            w2 = fmaf(hv, sW2[r*128 + 64 + lane], w2);
        }
        float u = 2.f*(elen*(1.f/MAXR) - 1.f);
        float cut = (u > 0.f) ? 0.f : 0.5f*(1.f - __cosf(PI_F*u));
        float coef = SQRT3 * cut * invSafe;
        float ea0 = coef*ex, ea1 = coef*ey, ea2 = coef*ez;
        const float* vp = v1 + (size_t)src*192 + lane*3;
        float dv = vp[0]*ea0 + vp[1]*ea1 + vp[2]*ea2;
        accS = fmaf(w2, dv, accS);
        if (withV) {
            float sv = s1[(size_t)src*64 + lane];
            float tt = w1*sv;
            av0 = fmaf(tt, ea0, av0); av1 = fmaf(tt, ea1, av1); av2 = fmaf(tt, ea2, av2);
        }
    }
    aggS[(size_t)node*64 + lane] = accS*INVNN;
    float* ap = aggV + (size_t)node*192 + lane*3;
    ap[0] = av0*INVNN; ap[1] = av1*INVNN; ap[2] = av2*INVNN;
}

// ---------------- out = lin2(agg) + sc(y) -> gating; gS/gV may alias aggS/aggV ----------------
__global__ __launch_bounds__(256) void kOut(const float* ys, const float* yv,
        const float* aggS, const float* aggV, const int* attr,
        const float* L2s, const float* L2v, const float* Ts, const float* Tv,
        float* gS, float* gV, int n) {
    __shared__ float sL2s[64*128], sL2v[64*64];
    int t = threadIdx.x;
    for (int i = t; i < 64*128; i += 256) sL2s[i] = L2s[i];
    for (int i = t; i < 64*64;  i += 256) sL2v[i] = L2v[i];
    __syncthreads();
    int lane = t & 63;
    int node = blockIdx.x*4 + (t >> 6);
    if (node >= n) return;
    int a = attr[node];
    const float* tS = Ts + (size_t)a*64*128;
    const float* tV = Tv + (size_t)a*64*64;
    float as_r = aggS[(size_t)node*64 + lane];
    float ys_r = ys[(size_t)node*64 + lane];
    const float* avp = aggV + (size_t)node*192 + lane*3;
    float av0 = avp[0], av1 = avp[1], av2 = avp[2];
    const float* yvp = yv + (size_t)node*192 + lane*3;
    float by0 = yvp[0], by1 = yvp[1], by2 = yvp[2];
    float oS0 = 0.f, oS1 = 0.f, ov0 = 0.f, ov1 = 0.f, ov2 = 0.f;
    #pragma unroll 4
    for (int c = 0; c < 64; ++c) {
        float asc = __shfl(as_r, c), ysc = __shfl(ys_r, c);
        float a0 = __shfl(av0, c), a1 = __shfl(av1, c), a2 = __shfl(av2, c);
        float b0 = __shfl(by0, c), b1 = __shfl(by1, c), b2 = __shfl(by2, c);
        float lsa = sL2s[c*128 + lane], lsb = sL2s[c*128 + 64 + lane];
        float lv  = sL2v[c*64 + lane];
        float tsa = tS[c*128 + lane], tsb = tS[c*128 + 64 + lane];
        float tv  = tV[c*64 + lane];
        oS0 = fmaf(asc, lsa, fmaf(ysc, tsa, oS0));
        oS1 = fmaf(asc, lsb, fmaf(ysc, tsb, oS1));
        ov0 = fmaf(a0, lv, fmaf(b0, tv, ov0));
        ov1 = fmaf(a1, lv, fmaf(b1, tv, ov1));
        ov2 = fmaf(a2, lv, fmaf(b2, tv, ov2));
    }
    float gs = silu_(oS0);
    float sg = sigm_(oS1);
    gS[(size_t)node*64 + lane] = gs;
    float* gp = gV + (size_t)node*192 + lane*3;
    gp[0] = sg*ov0; gp[1] = sg*ov1; gp[2] = sg*ov2;
}

// ---------------- combine: y2 = y@si ; new = 2y - yold + hh*(m*g + (m-1)*y2); x = newv.Q ----------------
__global__ __launch_bounds__(256) void kComb(const float* ys, const float* yv,
        const float* yolds, const float* yoldv, const float* gS, const float* gV,
        const float* siS, const float* siV, const float* Q,
        const float* hArr, const float* mArr, int li,
        float* newS, float* newV, float* xout, int n) {
    __shared__ float sSs[64*64], sSv[64*64];
    int t = threadIdx.x;
    for (int i = t; i < 4096; i += 256) { sSs[i] = siS[i]; sSv[i] = siV[i]; }
    __syncthreads();
    int lane = t & 63;
    int node = blockIdx.x*4 + (t >> 6);
    if (node >= n) return;
    float hh = hArr[li]; hh *= hh;
    float m = mArr[li];
    float ys_r = ys[(size_t)node*64 + lane];
    const float* yvp = yv + (size_t)node*192 + lane*3;
    float y0 = yvp[0], y1 = yvp[1], y2c = yvp[2];
    float q2s = 0.f, qv0 = 0.f, qv1 = 0.f, qv2 = 0.f;
    #pragma unroll 8
    for (int c = 0; c < 64; ++c) {
        float ysc = __shfl(ys_r, c);
        float b0 = __shfl(y0, c), b1 = __shfl(y1, c), b2 = __shfl(y2c, c);
        float ws = sSs[c*64 + lane], wv = sSv[c*64 + lane];
        q2s = fmaf(ysc, ws, q2s);
        qv0 = fmaf(b0, wv, qv0); qv1 = fmaf(b1, wv, qv1); qv2 = fmaf(b2, wv, qv2);
    }
    float yos = yolds[(size_t)node*64 + lane];
    const float* yop = yoldv + (size_t)node*192 + lane*3;
    float go = gS[(size_t)node*64 + lane];
    const float* gp = gV + (size_t)node*192 + lane*3;
    float ns  = 2.f*ys_r - yos   + hh*(m*go    + (m-1.f)*q2s);
    float nv0 = 2.f*y0  - yop[0] + hh*(m*gp[0] + (m-1.f)*qv0);
    float nv1 = 2.f*y1  - yop[1] + hh*(m*gp[1] + (m-1.f)*qv1);
    float nv2 = 2.f*y2c - yop[2] + hh*(m*gp[2] + (m-1.f)*qv2);
    newS[(size_t)node*64 + lane] = ns;
    float* np = newV + (size_t)node*192 + lane*3;
    np[0] = nv0; np[1] = nv1; np[2] = nv2;
    float q0 = Q[2*lane], q1 = Q[2*lane+1];
    float p00 = nv0*q0, p01 = nv1*q0, p02 = nv2*q0;
    float p10 = nv0*q1, p11 = nv1*q1, p12 = nv2*q1;
    for (int o = 32; o > 0; o >>= 1) {
        p00 += __shfl_xor(p00, o); p01 += __shfl_xor(p01, o); p02 += __shfl_xor(p02, o);
        p10 += __shfl_xor(p10, o); p11 += __shfl_xor(p11, o); p12 += __shfl_xor(p12, o);
    }
    if (lane == 0) {
        float* xp = xout + (size_t)node*6;
        xp[0] = p00; xp[1] = p01; xp[2] = p02;
        xp[3] = p10; xp[4] = p11; xp[5] = p12;
    }
}

extern "C" void kernel_launch(void* const* d_in, const int* in_sizes, int n_in,
                              void* d_out, int out_size, void* d_ws, size_t ws_size,
                              hipStream_t stream) {
    const float* x        = (const float*)d_in[0];
    const int*   nattr    = (const int*)  d_in[2];
    const int*   esrc     = (const int*)  d_in[3];
    const int*   edst     = (const int*)  d_in[4];
    const float* embT     = (const float*)d_in[5];
    const float* upM      = (const float*)d_in[6];
    const float* hArr     = (const float*)d_in[7];
    const float* mArr     = (const float*)d_in[8];
    const float* rW1      = (const float*)d_in[9];
    const float* rb1      = (const float*)d_in[10];
    const float* rW2      = (const float*)d_in[11];
    const float* l1s      = (const float*)d_in[12];
    const float* l1v      = (const float*)d_in[13];
    const float* l2s      = (const float*)d_in[14];
    const float* l2v      = (const float*)d_in[15];
    const float* scs      = (const float*)d_in[16];
    const float* scv      = (const float*)d_in[17];
    const float* sis      = (const float*)d_in[18];
    const float* siv      = (const float*)d_in[19];
    int n = in_sizes[0] / 6;
    int e = in_sizes[3];
    float* out = (float*)d_out;

    // ---- workspace carve ----
    float* w = (float*)d_ws;
    float* Q    = w; w += 128;
    float* yAs  = w; w += (size_t)n*64;
    float* yAv  = w; w += (size_t)n*192;
    float* yBs  = w; w += (size_t)n*64;
    float* yBv  = w; w += (size_t)n*192;
    float* s1   = w; w += (size_t)n*64;
    float* v1   = w; w += (size_t)n*192;
    float* aggS = w; w += (size_t)n*64;
    float* aggV = w; w += (size_t)n*192;
    float* xcur = w; w += (size_t)n*6;
    float* Ts   = w; w += (size_t)2*NATTR*64*128;
    float* Tv   = w; w += (size_t)2*NATTR*64*64;
    int* cnt       = (int*)w;
    int* offs      = cnt + n;
    int* cursor    = offs + (n + 1);
    int* srcSorted = cursor + n;
    size_t need = (size_t)((char*)(srcSorted + e) - (char*)d_ws);
    if (need > ws_size) {
        fprintf(stderr, "kernel_launch: ws too small (%zu > %zu)\n", need, ws_size);
        return;
    }

    int nb4 = (n + 3) / 4;

    kQ<<<1, 64, 0, stream>>>(upM, Q);
    kInit<<<(n*64 + 255)/256, 256, 0, stream>>>(x, Q, yAs, yAv, xcur, n);

    hipMemsetAsync(cnt, 0, (size_t)n*sizeof(int), stream);
    kHist<<<(e + 255)/256, 256, 0, stream>>>(edst, cnt, e);
    kScan<<<1, 1024, 0, stream>>>(cnt, offs, cursor, n);
    kScatter<<<(e + 255)/256, 256, 0, stream>>>(esrc, edst, cursor, srcSorted, e);

    kT<<<dim3(64, NATTR, 2), 192, 0, stream>>>(embT, scs, scv, Ts, Tv);

    for (int i = 0; i < 2; ++i) {
        const float* ysCur = (i == 0) ? yAs : yBs;
        const float* yvCur = (i == 0) ? yAv : yBv;
        const float* yoS = yAs;
        const float* yoV = yAv;
        float* nS = (i == 0) ? yBs : yAs;
        float* nV = (i == 0) ? yBv : yAv;
        float* xo = (i == 0) ? xcur : out;

        kLin1<<<nb4, 256, 0, stream>>>(ysCur, yvCur, l1s + i*4096, l1v + i*4096, s1, v1, n);
        kAgg<<<nb4, 256, 0, stream>>>(xcur, s1, v1, offs, srcSorted,
                                      rW1 + i*NBD*RHD, rb1 + i*RHD, rW2 + i*RHD*128,
                                      aggS, aggV, n, i > 0 ? 1 : 0);
        kOut<<<nb4, 256, 0, stream>>>(ysCur, yvCur, aggS, aggV, nattr,
                                      l2s + (size_t)i*64*128, l2v + (size_t)i*64*64,
                                      Ts + (size_t)i*NATTR*64*128, Tv + (size_t)i*NATTR*64*64,
                                      aggS, aggV, n);   // gating output aliases agg buffers
        kComb<<<nb4, 256, 0, stream>>>(ysCur, yvCur, yoS, yoV, aggS, aggV,
                                       sis + i*4096, siv + i*4096, Q, hArr, mArr, i,
                                       nS, nV, xo, n);
    }
}

// Round 2
// 1349.698 us; speedup vs baseline: 1.0983x; 1.0983x over previous
//
#include <hip/hip_runtime.h>
#include <cstdio>
#include <cstdint>

#define CCH 64      // channels C
#define EMBD 32     // embedding dim
#define NBD 8       // num radial basis
#define RHD 32      // radial hidden
#define NATTR 100   // distinct node_attr values

static constexpr float MAXR    = 2.5f;
static constexpr float INVNN   = 0.17677669529663687f;  // 1/sqrt(32)
static constexpr float EFK     = 2.5298221281347035f;   // sqrt(2/2.5)*sqrt(8)
static constexpr float SQRT3   = 1.7320508075688772f;
static constexpr float PI_F    = 3.14159265358979323846f;

__device__ __forceinline__ float sigm_(float x) { return 1.f / (1.f + __expf(-x)); }
__device__ __forceinline__ float silu_(float x) { return x / (1.f + __expf(-x)); }

// ---------------- Q = polar factor of uplift_M (64x2) ----------------
__global__ void kQ(const float* M, float* Q) {
    int c = threadIdx.x;  // 64 threads = 1 wave
    float m0 = M[2*c], m1 = M[2*c+1];
    float a = m0*m0, b = m0*m1, d = m1*m1;
    for (int o = 32; o > 0; o >>= 1) {
        a += __shfl_xor(a, o); b += __shfl_xor(b, o); d += __shfl_xor(d, o);
    }
    float det = a*d - b*b;
    float s = sqrtf(det);
    float t = sqrtf(a + d + 2.f*s);
    float inv = 1.f / (s*t);
    float i00 = (d + s)*inv, i01 = -b*inv, i11 = (a + s)*inv;
    Q[2*c]   = m0*i00 + m1*i01;
    Q[2*c+1] = m0*i01 + m1*i11;
}

// ---------------- init y, xcur ----------------
__global__ void kInit(const float* x, const float* Q, float* yAs, float* yAv,
                      float* xcur, int n) {
    int tid = blockIdx.x*blockDim.x + threadIdx.x;
    int node = tid >> 6, c = tid & 63;
    if (node >= n) return;
    const float* xr = x + (size_t)node*6;
    float q0 = Q[2*c], q1 = Q[2*c+1];
    float* yv = yAv + (size_t)node*192 + c*3;
    yv[0] = q0*xr[0] + q1*xr[3];
    yv[1] = q0*xr[1] + q1*xr[4];
    yv[2] = q0*xr[2] + q1*xr[5];
    yAs[(size_t)node*64 + c] = 0.f;
    if (c < 6) xcur[(size_t)node*6 + c] = xr[c];
}

// ---------------- CSR build ----------------
__global__ void kHist(const int* dst, int* cnt, int e) {
    int i = blockIdx.x*blockDim.x + threadIdx.x;
    if (i < e) atomicAdd(&cnt[dst[i]], 1);
}

__global__ void kScan(const int* cnt, int* offs, int* cursor, int n) {
    __shared__ int part[1024];
    int t = threadIdx.x;
    int chunk = (n + 1023) >> 10;
    int lo = t*chunk, hi = min(lo + chunk, n);
    int s = 0;
    for (int i = lo; i < hi; ++i) s += cnt[i];
    part[t] = s;
    __syncthreads();
    for (int o = 1; o < 1024; o <<= 1) {
        int w = (t >= o) ? part[t - o] : 0;
        __syncthreads();
        part[t] += w;
        __syncthreads();
    }
    int run = part[t] - s;  // exclusive prefix of this thread's chunk
    for (int i = lo; i < hi; ++i) {
        int cv = cnt[i];
        offs[i] = run; cursor[i] = run;
        run += cv;
    }
    if (t == 1023) offs[n] = part[1023];
}

__global__ void kScatter(const int* src, const int* dst, int* cursor,
                         int* srcSorted, int e) {
    int i = blockIdx.x*blockDim.x + threadIdx.x;
    if (i < e) {
        int p = atomicAdd(&cursor[dst[i]], 1);
        srcSorted[p] = src[i];
    }
}

// ---------------- T tables: contract emb_table into sc weights ----------------
__global__ void kT(const float* embT, const float* scs, const float* scv,
                   float* Ts, float* Tv) {
    int c = blockIdx.x, a = blockIdx.y, l = blockIdx.z;
    int t = threadIdx.x;  // 192 threads
    const float* e = embT + a*EMBD;
    if (t < 128) {
        const float* w = scs + ((size_t)(l*CCH + c)*EMBD)*128 + t;
        float acc = 0.f;
        #pragma unroll
        for (int k = 0; k < EMBD; ++k) acc += e[k]*w[(size_t)k*128];
        Ts[(((size_t)l*NATTR + a)*CCH + c)*128 + t] = acc;
    } else {
        int o = t - 128;
        const float* w = scv + ((size_t)(l*CCH + c)*EMBD)*64 + o;
        float acc = 0.f;
        #pragma unroll
        for (int k = 0; k < EMBD; ++k) acc += e[k]*w[(size_t)k*64];
        Tv[(((size_t)l*NATTR + a)*CCH + c)*64 + o] = acc;
    }
}

// ---------------- lin1: s1 = ys@L1s ; v1 = yv . L1v ----------------
__global__ __launch_bounds__(256) void kLin1(const float* __restrict__ ys, const float* __restrict__ yv,
        const float* __restrict__ L1s, const float* __restrict__ L1v,
        float* __restrict__ s1, float* __restrict__ v1, int n) {
    __shared__ float sLs[64*64], sLv[64*64];
    int t = threadIdx.x;
    for (int i = t; i < 4096; i += 256) { sLs[i] = L1s[i]; sLv[i] = L1v[i]; }
    __syncthreads();
    int lane = t & 63;
    int node = blockIdx.x*4 + (t >> 6);
    if (node >= n) return;
    float ys_r = ys[(size_t)node*64 + lane];
    const float* yvp = yv + (size_t)node*192 + lane*3;
    float y0 = yvp[0], y1 = yvp[1], y2 = yvp[2];
    float asA=0.f, asB=0.f, a0A=0.f, a0B=0.f, a1A=0.f, a1B=0.f, a2A=0.f, a2B=0.f;
    #pragma unroll 8
    for (int c = 0; c < 64; c += 2) {
        float ysc0 = __shfl(ys_r, c),  ysc1 = __shfl(ys_r, c+1);
        float b00 = __shfl(y0, c), b01 = __shfl(y1, c), b02 = __shfl(y2, c);
        float b10 = __shfl(y0, c+1), b11 = __shfl(y1, c+1), b12 = __shfl(y2, c+1);
        float ws0 = sLs[c*64 + lane], wv0 = sLv[c*64 + lane];
        float ws1 = sLs[(c+1)*64 + lane], wv1 = sLv[(c+1)*64 + lane];
        asA = fmaf(ysc0, ws0, asA); asB = fmaf(ysc1, ws1, asB);
        a0A = fmaf(b00, wv0, a0A);  a0B = fmaf(b10, wv1, a0B);
        a1A = fmaf(b01, wv0, a1A);  a1B = fmaf(b11, wv1, a1B);
        a2A = fmaf(b02, wv0, a2A);  a2B = fmaf(b12, wv1, a2B);
    }
    s1[(size_t)node*64 + lane] = asA + asB;
    float* vp = v1 + (size_t)node*192 + lane*3;
    vp[0] = a0A + a0B; vp[1] = a1A + a1B; vp[2] = a2A + a2B;
}

// ---------------- aggregation: 4 waves per dst node, lane = channel ----------------
template<int WITHV>
__global__ __launch_bounds__(256) void kAggT(const float* __restrict__ xcur, const float* __restrict__ s1,
        const float* __restrict__ v1, const int* __restrict__ offs, const int* __restrict__ srcSorted,
        const float* __restrict__ rW1, const float* __restrict__ rb1, const float* __restrict__ rW2,
        float* __restrict__ aggS, float* __restrict__ aggV, int n) {
    __shared__ float sW1[NBD*RHD];
    __shared__ float sB1[RHD];
    __shared__ float sW2[RHD*128];
    __shared__ float red[4][64][4];
    int t = threadIdx.x;
    for (int i = t; i < NBD*RHD; i += 256) sW1[i] = rW1[i];
    if (t < RHD) sB1[t] = rb1[t];
    for (int i = t; i < RHD*128; i += 256) sW2[i] = rW2[i];
    __syncthreads();
    int lane = t & 63;
    int wid = t >> 6;
    int lh = lane & 31;
    for (int node = blockIdx.x; node < n; node += gridDim.x) {
        float px = xcur[(size_t)node*6+0], py = xcur[(size_t)node*6+1], pz = xcur[(size_t)node*6+2];
        int beg = offs[node], end = offs[node+1];
        float accS = 0.f, av0 = 0.f, av1 = 0.f, av2 = 0.f;
        int idx = beg + wid;
        // 2-deep pipeline: src prefetched 2 ahead, position 1 ahead
        int srcA = 0, srcB = 0;
        float pex = 0.f, pey = 0.f, pez = 0.f;
        if (idx < end) srcA = srcSorted[idx];
        if (idx + 4 < end) srcB = srcSorted[idx + 4];
        if (idx < end) {
            const float* sp = xcur + (size_t)srcA*6;
            pex = sp[0]; pey = sp[1]; pez = sp[2];
        }
        for (; idx < end; idx += 4) {
            int srcU = srcA;
            float ex = pex - px, ey = pey - py, ez = pez - pz;
            // advance pipeline (srcA already resident -> pos load issues immediately)
            srcA = srcB;
            if (idx + 8 < end) srcB = srcSorted[idx + 8];
            if (idx + 4 < end) {
                const float* sp = xcur + (size_t)srcA*6;
                pex = sp[0]; pey = sp[1]; pez = sp[2];
            }
            float el2 = ex*ex + ey*ey + ez*ez;
            if (el2 >= MAXR*MAXR) continue;   // wave-uniform skip: cut == 0
            // issue gathers early
            const float* vp = v1 + (size_t)srcU*192 + lane*3;
            float vv0 = vp[0], vv1 = vp[1], vv2 = vp[2];
            float sv = 0.f;
            if (WITHV) sv = s1[(size_t)srcU*64 + lane];
            float elen = sqrtf(el2);
            float safe = fmaxf(elen, 1e-9f);
            float invSafe = 1.f/safe;
            float th = PI_F * safe * (1.f/MAXR);
            float s0, c0;
            __sincosf(th, &s0, &c0);
            // hidden units (all lanes compute duplicate copy; shfl reads lanes 0..31)
            float hid = sB1[lh];
            {
                float sPrev = 0.f, sCur = s0, twoC = 2.f*c0;
                #pragma unroll
                for (int b = 0; b < NBD; ++b) {        // ef[b] ~ sin((b+1)*th)
                    float efb = EFK * sCur * invSafe;
                    hid = fmaf(efb, sW1[b*RHD + lh], hid);
                    float sN = fmaf(twoC, sCur, -sPrev);
                    sPrev = sCur; sCur = sN;
                }
            }
            hid = silu_(hid);
            // w = hid @ W2 : 4-way accumulator split (fma chain 32 -> 8)
            float w1a=0.f, w1b=0.f, w1c=0.f, w1d=0.f;
            float w2a=0.f, w2b=0.f, w2c=0.f, w2d=0.f;
            #pragma unroll
            for (int r = 0; r < RHD; r += 4) {
                float h0 = __shfl(hid, r),   h1 = __shfl(hid, r+1);
                float h2 = __shfl(hid, r+2), h3 = __shfl(hid, r+3);
                if (WITHV) {
                    w1a = fmaf(h0, sW2[ r   *128 + lane], w1a);
                    w1b = fmaf(h1, sW2[(r+1)*128 + lane], w1b);
                    w1c = fmaf(h2, sW2[(r+2)*128 + lane], w1c);
                    w1d = fmaf(h3, sW2[(r+3)*128 + lane], w1d);
                }
                w2a = fmaf(h0, sW2[ r   *128 + 64 + lane], w2a);
                w2b = fmaf(h1, sW2[(r+1)*128 + 64 + lane], w2b);
                w2c = fmaf(h2, sW2[(r+2)*128 + 64 + lane], w2c);
                w2d = fmaf(h3, sW2[(r+3)*128 + 64 + lane], w2d);
            }
            float w2 = (w2a + w2b) + (w2c + w2d);
            float u = 2.f*(elen*(1.f/MAXR) - 1.f);
            float cut = (u > 0.f) ? 0.f : 0.5f*(1.f - __cosf(PI_F*u));
            float coef = SQRT3 * cut * invSafe;
            float ea0 = coef*ex, ea1 = coef*ey, ea2 = coef*ez;
            float dv = vv0*ea0 + vv1*ea1 + vv2*ea2;
            accS = fmaf(w2, dv, accS);
            if (WITHV) {
                float w1 = (w1a + w1b) + (w1c + w1d);
                float tt = w1*sv;
                av0 = fmaf(tt, ea0, av0); av1 = fmaf(tt, ea1, av1); av2 = fmaf(tt, ea2, av2);
            }
        }
        red[wid][lane][0] = accS; red[wid][lane][1] = av0;
        red[wid][lane][2] = av1;  red[wid][lane][3] = av2;
        __syncthreads();
        if (wid == 0) {
            float rs = red[0][lane][0] + red[1][lane][0] + red[2][lane][0] + red[3][lane][0];
            aggS[(size_t)node*64 + lane] = rs*INVNN;
            float r0 = red[0][lane][1] + red[1][lane][1] + red[2][lane][1] + red[3][lane][1];
            float r1 = red[0][lane][2] + red[1][lane][2] + red[2][lane][2] + red[3][lane][2];
            float r2 = red[0][lane][3] + red[1][lane][3] + red[2][lane][3] + red[3][lane][3];
            float* ap = aggV + (size_t)node*192 + lane*3;
            ap[0] = r0*INVNN; ap[1] = r1*INVNN; ap[2] = r2*INVNN;
        }
        __syncthreads();
    }
}

// ---------------- out = lin2(agg) + sc(y) -> gating; gS/gV may alias aggS/aggV ----------------
__global__ __launch_bounds__(256) void kOut(const float* __restrict__ ys, const float* __restrict__ yv,
        const float* __restrict__ aggS, const float* __restrict__ aggV, const int* __restrict__ attr,
        const float* __restrict__ L2s, const float* __restrict__ L2v,
        const float* __restrict__ Ts, const float* __restrict__ Tv,
        float* __restrict__ gS, float* __restrict__ gV, int n) {
    __shared__ float sL2s[64*128], sL2v[64*64];
    int t = threadIdx.x;
    for (int i = t; i < 64*128; i += 256) sL2s[i] = L2s[i];
    for (int i = t; i < 64*64;  i += 256) sL2v[i] = L2v[i];
    __syncthreads();
    int lane = t & 63;
    int node = blockIdx.x*4 + (t >> 6);
    if (node >= n) return;
    int a = attr[node];
    const float* tS = Ts + (size_t)a*64*128;
    const float* tV = Tv + (size_t)a*64*64;
    float as_r = aggS[(size_t)node*64 + lane];
    float ys_r = ys[(size_t)node*64 + lane];
    const float* avp = aggV + (size_t)node*192 + lane*3;
    float av0 = avp[0], av1 = avp[1], av2 = avp[2];
    const float* yvp = yv + (size_t)node*192 + lane*3;
    float by0 = yvp[0], by1 = yvp[1], by2 = yvp[2];
    float oS0A=0.f,oS0B=0.f, oS1A=0.f,oS1B=0.f;
    float ov0A=0.f,ov0B=0.f, ov1A=0.f,ov1B=0.f, ov2A=0.f,ov2B=0.f;
    #pragma unroll 4
    for (int c = 0; c < 64; c += 2) {
        float asc0 = __shfl(as_r, c), ysc0 = __shfl(ys_r, c);
        float asc1 = __shfl(as_r, c+1), ysc1 = __shfl(ys_r, c+1);
        float a00 = __shfl(av0, c), a01 = __shfl(av1, c), a02 = __shfl(av2, c);
        float a10 = __shfl(av0, c+1), a11 = __shfl(av1, c+1), a12 = __shfl(av2, c+1);
        float b00 = __shfl(by0, c), b01 = __shfl(by1, c), b02 = __shfl(by2, c);
        float b10 = __shfl(by0, c+1), b11 = __shfl(by1, c+1), b12 = __shfl(by2, c+1);
        float lsa0 = sL2s[c*128 + lane], lsb0 = sL2s[c*128 + 64 + lane];
        float lsa1 = sL2s[(c+1)*128 + lane], lsb1 = sL2s[(c+1)*128 + 64 + lane];
        float lv0  = sL2v[c*64 + lane], lv1 = sL2v[(c+1)*64 + lane];
        float tsa0 = tS[c*128 + lane], tsb0 = tS[c*128 + 64 + lane];
        float tsa1 = tS[(c+1)*128 + lane], tsb1 = tS[(c+1)*128 + 64 + lane];
        float tv0  = tV[c*64 + lane], tv1 = tV[(c+1)*64 + lane];
        oS0A = fmaf(asc0, lsa0, fmaf(ysc0, tsa0, oS0A));
        oS0B = fmaf(asc1, lsa1, fmaf(ysc1, tsa1, oS0B));
        oS1A = fmaf(asc0, lsb0, fmaf(ysc0, tsb0, oS1A));
        oS1B = fmaf(asc1, lsb1, fmaf(ysc1, tsb1, oS1B));
        ov0A = fmaf(a00, lv0, fmaf(b00, tv0, ov0A));
        ov0B = fmaf(a10, lv1, fmaf(b10, tv1, ov0B));
        ov1A = fmaf(a01, lv0, fmaf(b01, tv0, ov1A));
        ov1B = fmaf(a11, lv1, fmaf(b11, tv1, ov1B));
        ov2A = fmaf(a02, lv0, fmaf(b02, tv0, ov2A));
        ov2B = fmaf(a12, lv1, fmaf(b12, tv1, ov2B));
    }
    float gs = silu_(oS0A + oS0B);
    float sg = sigm_(oS1A + oS1B);
    gS[(size_t)node*64 + lane] = gs;
    float* gp = gV + (size_t)node*192 + lane*3;
    gp[0] = sg*(ov0A+ov0B); gp[1] = sg*(ov1A+ov1B); gp[2] = sg*(ov2A+ov2B);
}

// ---------------- combine ----------------
__global__ __launch_bounds__(256) void kComb(const float* __restrict__ ys, const float* __restrict__ yv,
        const float* __restrict__ yolds, const float* __restrict__ yoldv,
        const float* __restrict__ gS, const float* __restrict__ gV,
        const float* __restrict__ siS, const float* __restrict__ siV, const float* __restrict__ Q,
        const float* __restrict__ hArr, const float* __restrict__ mArr, int li,
        float* __restrict__ newS, float* __restrict__ newV, float* __restrict__ xout, int n) {
    __shared__ float sSs[64*64], sSv[64*64];
    int t = threadIdx.x;
    for (int i = t; i < 4096; i += 256) { sSs[i] = siS[i]; sSv[i] = siV[i]; }
    __syncthreads();
    int lane = t & 63;
    int node = blockIdx.x*4 + (t >> 6);
    if (node >= n) return;
    float hh = hArr[li]; hh *= hh;
    float m = mArr[li];
    float ys_r = ys[(size_t)node*64 + lane];
    const float* yvp = yv + (size_t)node*192 + lane*3;
    float y0 = yvp[0], y1 = yvp[1], y2c = yvp[2];
    float q2sA=0.f,q2sB=0.f, qv0A=0.f,qv0B=0.f, qv1A=0.f,qv1B=0.f, qv2A=0.f,qv2B=0.f;
    #pragma unroll 8
    for (int c = 0; c < 64; c += 2) {
        float ysc0 = __shfl(ys_r, c), ysc1 = __shfl(ys_r, c+1);
        float b00 = __shfl(y0, c), b01 = __shfl(y1, c), b02 = __shfl(y2c, c);
        float b10 = __shfl(y0, c+1), b11 = __shfl(y1, c+1), b12 = __shfl(y2c, c+1);
        float ws0 = sSs[c*64 + lane], wv0 = sSv[c*64 + lane];
        float ws1 = sSs[(c+1)*64 + lane], wv1 = sSv[(c+1)*64 + lane];
        q2sA = fmaf(ysc0, ws0, q2sA); q2sB = fmaf(ysc1, ws1, q2sB);
        qv0A = fmaf(b00, wv0, qv0A);  qv0B = fmaf(b10, wv1, qv0B);
        qv1A = fmaf(b01, wv0, qv1A);  qv1B = fmaf(b11, wv1, qv1B);
        qv2A = fmaf(b02, wv0, qv2A);  qv2B = fmaf(b12, wv1, qv2B);
    }
    float q2s = q2sA+q2sB, qv0 = qv0A+qv0B, qv1 = qv1A+qv1B, qv2 = qv2A+qv2B;
    float yos = yolds[(size_t)node*64 + lane];
    const float* yop = yoldv + (size_t)node*192 + lane*3;
    float go = gS[(size_t)node*64 + lane];
    const float* gp = gV + (size_t)node*192 + lane*3;
    float ns  = 2.f*ys_r - yos   + hh*(m*go    + (m-1.f)*q2s);
    float nv0 = 2.f*y0  - yop[0] + hh*(m*gp[0] + (m-1.f)*qv0);
    float nv1 = 2.f*y1  - yop[1] + hh*(m*gp[1] + (m-1.f)*qv1);
    float nv2 = 2.f*y2c - yop[2] + hh*(m*gp[2] + (m-1.f)*qv2);
    newS[(size_t)node*64 + lane] = ns;
    float* np = newV + (size_t)node*192 + lane*3;
    np[0] = nv0; np[1] = nv1; np[2] = nv2;
    float q0 = Q[2*lane], q1 = Q[2*lane+1];
    float p00 = nv0*q0, p01 = nv1*q0, p02 = nv2*q0;
    float p10 = nv0*q1, p11 = nv1*q1, p12 = nv2*q1;
    for (int o = 32; o > 0; o >>= 1) {
        p00 += __shfl_xor(p00, o); p01 += __shfl_xor(p01, o); p02 += __shfl_xor(p02, o);
        p10 += __shfl_xor(p10, o); p11 += __shfl_xor(p11, o); p12 += __shfl_xor(p12, o);
    }
    if (lane == 0) {
        float* xp = xout + (size_t)node*6;
        xp[0] = p00; xp[1] = p01; xp[2] = p02;
        xp[3] = p10; xp[4] = p11; xp[5] = p12;
    }
}

extern "C" void kernel_launch(void* const* d_in, const int* in_sizes, int n_in,
                              void* d_out, int out_size, void* d_ws, size_t ws_size,
                              hipStream_t stream) {
    const float* x        = (const float*)d_in[0];
    const int*   nattr    = (const int*)  d_in[2];
    const int*   esrc     = (const int*)  d_in[3];
    const int*   edst     = (const int*)  d_in[4];
    const float* embT     = (const float*)d_in[5];
    const float* upM      = (const float*)d_in[6];
    const float* hArr     = (const float*)d_in[7];
    const float* mArr     = (const float*)d_in[8];
    const float* rW1      = (const float*)d_in[9];
    const float* rb1      = (const float*)d_in[10];
    const float* rW2      = (const float*)d_in[11];
    const float* l1s      = (const float*)d_in[12];
    const float* l1v      = (const float*)d_in[13];
    const float* l2s      = (const float*)d_in[14];
    const float* l2v      = (const float*)d_in[15];
    const float* scs      = (const float*)d_in[16];
    const float* scv      = (const float*)d_in[17];
    const float* sis      = (const float*)d_in[18];
    const float* siv      = (const float*)d_in[19];
    int n = in_sizes[0] / 6;
    int e = in_sizes[3];
    float* out = (float*)d_out;

    // ---- workspace carve ----
    float* w = (float*)d_ws;
    float* Q    = w; w += 128;
    float* yAs  = w; w += (size_t)n*64;
    float* yAv  = w; w += (size_t)n*192;
    float* yBs  = w; w += (size_t)n*64;
    float* yBv  = w; w += (size_t)n*192;
    float* s1   = w; w += (size_t)n*64;
    float* v1   = w; w += (size_t)n*192;
    float* aggS = w; w += (size_t)n*64;
    float* aggV = w; w += (size_t)n*192;
    float* xcur = w; w += (size_t)n*6;
    float* Ts   = w; w += (size_t)2*NATTR*64*128;
    float* Tv   = w; w += (size_t)2*NATTR*64*64;
    int* cnt       = (int*)w;
    int* offs      = cnt + n;
    int* cursor    = offs + (n + 1);
    int* srcSorted = cursor + n;
    size_t need = (size_t)((char*)(srcSorted + e) - (char*)d_ws);
    if (need > ws_size) {
        fprintf(stderr, "kernel_launch: ws too small (%zu > %zu)\n", need, ws_size);
        return;
    }

    int nb4 = (n + 3) / 4;
    const int AGG_GRID = 1792;   // 7 blocks/CU by LDS (21.6 KB/block)

    kQ<<<1, 64, 0, stream>>>(upM, Q);
    kInit<<<(n*64 + 255)/256, 256, 0, stream>>>(x, Q, yAs, yAv, xcur, n);

    hipMemsetAsync(cnt, 0, (size_t)n*sizeof(int), stream);
    kHist<<<(e + 255)/256, 256, 0, stream>>>(edst, cnt, e);
    kScan<<<1, 1024, 0, stream>>>(cnt, offs, cursor, n);
    kScatter<<<(e + 255)/256, 256, 0, stream>>>(esrc, edst, cursor, srcSorted, e);

    kT<<<dim3(64, NATTR, 2), 192, 0, stream>>>(embT, scs, scv, Ts, Tv);

    for (int i = 0; i < 2; ++i) {
        const float* ysCur = (i == 0) ? yAs : yBs;
        const float* yvCur = (i == 0) ? yAv : yBv;
        const float* yoS = yAs;
        const float* yoV = yAv;
        float* nS = (i == 0) ? yBs : yAs;
        float* nV = (i == 0) ? yBv : yAv;
        float* xo = (i == 0) ? xcur : out;

        kLin1<<<nb4, 256, 0, stream>>>(ysCur, yvCur, l1s + i*4096, l1v + i*4096, s1, v1, n);
        if (i == 0)
            kAggT<0><<<AGG_GRID, 256, 0, stream>>>(xcur, s1, v1, offs, srcSorted,
                                        rW1 + i*NBD*RHD, rb1 + i*RHD, rW2 + i*RHD*128,
                                        aggS, aggV, n);
        else
            kAggT<1><<<AGG_GRID, 256, 0, stream>>>(xcur, s1, v1, offs, srcSorted,
                                        rW1 + i*NBD*RHD, rb1 + i*RHD, rW2 + i*RHD*128,
                                        aggS, aggV, n);
        kOut<<<nb4, 256, 0, stream>>>(ysCur, yvCur, aggS, aggV, nattr,
                                      l2s + (size_t)i*64*128, l2v + (size_t)i*64*64,
                                      Ts + (size_t)i*NATTR*64*128, Tv + (size_t)i*NATTR*64*64,
                                      aggS, aggV, n);   // gating output aliases agg buffers
        kComb<<<nb4, 256, 0, stream>>>(ysCur, yvCur, yoS, yoV, aggS, aggV,
                                       sis + i*4096, siv + i*4096, Q, hArr, mArr, i,
                                       nS, nV, xo, n);
    }
}

// Round 3
// 1138.216 us; speedup vs baseline: 1.3024x; 1.1858x over previous
//
#include <hip/hip_runtime.h>
#include <cstdio>
#include <cstdint>

#define CCH 64      // channels C
#define EMBD 32     // embedding dim
#define NBD 8       // num radial basis
#define RHD 32      // radial hidden
#define NATTR 100   // distinct node_attr values

static constexpr float MAXR    = 2.5f;
static constexpr float INVNN   = 0.17677669529663687f;  // 1/sqrt(32)
static constexpr float EFK     = 2.5298221281347035f;   // sqrt(2/2.5)*sqrt(8)
static constexpr float SQRT3   = 1.7320508075688772f;
static constexpr float PI_F    = 3.14159265358979323846f;

typedef float v2f __attribute__((ext_vector_type(2)));

__device__ __forceinline__ float sigm_(float x) { return 1.f / (1.f + __expf(-x)); }
__device__ __forceinline__ float silu_(float x) { return x / (1.f + __expf(-x)); }
__device__ __forceinline__ float rdlane(float v, int l) {
    return __uint_as_float(__builtin_amdgcn_readlane(__float_as_uint(v), l));
}

// ---------------- Q = polar factor of uplift_M (64x2) ----------------
__global__ void kQ(const float* M, float* Q) {
    int c = threadIdx.x;  // 64 threads = 1 wave
    float m0 = M[2*c], m1 = M[2*c+1];
    float a = m0*m0, b = m0*m1, d = m1*m1;
    for (int o = 32; o > 0; o >>= 1) {
        a += __shfl_xor(a, o); b += __shfl_xor(b, o); d += __shfl_xor(d, o);
    }
    float det = a*d - b*b;
    float s = sqrtf(det);
    float t = sqrtf(a + d + 2.f*s);
    float inv = 1.f / (s*t);
    float i00 = (d + s)*inv, i01 = -b*inv, i11 = (a + s)*inv;
    Q[2*c]   = m0*i00 + m1*i01;
    Q[2*c+1] = m0*i01 + m1*i11;
}

// ---------------- init y, xcur ----------------
__global__ void kInit(const float* x, const float* Q, float* yAs, float* yAv,
                      float* xcur, int n) {
    int tid = blockIdx.x*blockDim.x + threadIdx.x;
    int node = tid >> 6, c = tid & 63;
    if (node >= n) return;
    const float* xr = x + (size_t)node*6;
    float q0 = Q[2*c], q1 = Q[2*c+1];
    float* yv = yAv + (size_t)node*192 + c*3;
    yv[0] = q0*xr[0] + q1*xr[3];
    yv[1] = q0*xr[1] + q1*xr[4];
    yv[2] = q0*xr[2] + q1*xr[5];
    yAs[(size_t)node*64 + c] = 0.f;
    if (c < 6) xcur[(size_t)node*6 + c] = xr[c];
}

// ---------------- CSR build ----------------
__global__ void kHist(const int* dst, int* cnt, int e) {
    int i = blockIdx.x*blockDim.x + threadIdx.x;
    if (i < e) atomicAdd(&cnt[dst[i]], 1);
}

__global__ void kScan(const int* cnt, int* offs, int* cursor, int n) {
    __shared__ int part[1024];
    int t = threadIdx.x;
    int chunk = (n + 1023) >> 10;
    int lo = t*chunk, hi = min(lo + chunk, n);
    int s = 0;
    for (int i = lo; i < hi; ++i) s += cnt[i];
    part[t] = s;
    __syncthreads();
    for (int o = 1; o < 1024; o <<= 1) {
        int w = (t >= o) ? part[t - o] : 0;
        __syncthreads();
        part[t] += w;
        __syncthreads();
    }
    int run = part[t] - s;
    for (int i = lo; i < hi; ++i) {
        int cv = cnt[i];
        offs[i] = run; cursor[i] = run;
        run += cv;
    }
    if (t == 1023) offs[n] = part[1023];
}

__global__ void kScatter(const int* src, const int* dst, int* cursor,
                         int* srcSorted, int e) {
    int i = blockIdx.x*blockDim.x + threadIdx.x;
    if (i < e) {
        int p = atomicAdd(&cursor[dst[i]], 1);
        srcSorted[p] = src[i];
    }
}

// ---------------- T tables: contract emb_table into sc weights ----------------
__global__ void kT(const float* embT, const float* scs, const float* scv,
                   float* Ts, float* Tv) {
    int c = blockIdx.x, a = blockIdx.y, l = blockIdx.z;
    int t = threadIdx.x;  // 192 threads
    const float* e = embT + a*EMBD;
    if (t < 128) {
        const float* w = scs + ((size_t)(l*CCH + c)*EMBD)*128 + t;
        float acc = 0.f;
        #pragma unroll
        for (int k = 0; k < EMBD; ++k) acc += e[k]*w[(size_t)k*128];
        Ts[(((size_t)l*NATTR + a)*CCH + c)*128 + t] = acc;
    } else {
        int o = t - 128;
        const float* w = scv + ((size_t)(l*CCH + c)*EMBD)*64 + o;
        float acc = 0.f;
        #pragma unroll
        for (int k = 0; k < EMBD; ++k) acc += e[k]*w[(size_t)k*64];
        Tv[(((size_t)l*NATTR + a)*CCH + c)*64 + o] = acc;
    }
}

// ---------------- lin1: s1 = ys@L1s ; v1 = yv . L1v (persistent) ----------------
__global__ __launch_bounds__(256) void kLin1(const float* __restrict__ ys, const float* __restrict__ yv,
        const float* __restrict__ L1s, const float* __restrict__ L1v,
        float* __restrict__ s1, float* __restrict__ v1, int n) {
    __shared__ float sLs[64*64], sLv[64*64];
    int t = threadIdx.x;
    for (int i = t; i < 4096; i += 256) { sLs[i] = L1s[i]; sLv[i] = L1v[i]; }
    __syncthreads();
    int lane = t & 63;
    int wid = t >> 6;
    for (int node = blockIdx.x*4 + wid; node < n; node += gridDim.x*4) {
        float ys_r = ys[(size_t)node*64 + lane];
        const float* yvp = yv + (size_t)node*192 + lane*3;
        float y0 = yvp[0], y1 = yvp[1], y2 = yvp[2];
        float asA=0.f, asB=0.f, a0A=0.f, a0B=0.f, a1A=0.f, a1B=0.f, a2A=0.f, a2B=0.f;
        #pragma unroll 8
        for (int c = 0; c < 64; c += 2) {
            float ysc0 = __shfl(ys_r, c),  ysc1 = __shfl(ys_r, c+1);
            float b00 = __shfl(y0, c), b01 = __shfl(y1, c), b02 = __shfl(y2, c);
            float b10 = __shfl(y0, c+1), b11 = __shfl(y1, c+1), b12 = __shfl(y2, c+1);
            float ws0 = sLs[c*64 + lane], wv0 = sLv[c*64 + lane];
            float ws1 = sLs[(c+1)*64 + lane], wv1 = sLv[(c+1)*64 + lane];
            asA = fmaf(ysc0, ws0, asA); asB = fmaf(ysc1, ws1, asB);
            a0A = fmaf(b00, wv0, a0A);  a0B = fmaf(b10, wv1, a0B);
            a1A = fmaf(b01, wv0, a1A);  a1B = fmaf(b11, wv1, a1B);
            a2A = fmaf(b02, wv0, a2A);  a2B = fmaf(b12, wv1, a2B);
        }
        s1[(size_t)node*64 + lane] = asA + asB;
        float* vp = v1 + (size_t)node*192 + lane*3;
        vp[0] = a0A + a0B; vp[1] = a1A + a1B; vp[2] = a2A + a2B;
    }
}

// ---------------- aggregation: 4 waves/node, radial weights in REGISTERS ----------------
// s1 == 0 at layer 0, so the msg_v path self-disables; one unified kernel.
__global__ __launch_bounds__(256, 4) void kAgg(const float* __restrict__ xcur,
        const float* __restrict__ s1, const float* __restrict__ v1,
        const int* __restrict__ offs, const int* __restrict__ srcSorted,
        const float* __restrict__ rW1, const float* __restrict__ rb1, const float* __restrict__ rW2,
        float* __restrict__ aggS, float* __restrict__ aggV, int n) {
    __shared__ float red[4][64][4];
    int t = threadIdx.x;
    int lane = t & 63;
    int wid = t >> 6;
    int lh = lane & 31;
    // register-cached radial weights (edge-invariant): no LDS in the hot loop
    float w1e[NBD];
    #pragma unroll
    for (int b = 0; b < NBD; ++b) w1e[b] = EFK * rW1[b*RHD + lh];
    float b1r = rb1[lh];
    v2f wc[RHD];   // {W2[r][lane] (->msg_v), W2[r][64+lane] (->msg_s)}
    #pragma unroll
    for (int r = 0; r < RHD; ++r)
        wc[r] = (v2f){ rW2[r*128 + lane], rW2[r*128 + 64 + lane] };

    for (int node = blockIdx.x; node < n; node += gridDim.x) {
        float px = xcur[(size_t)node*6+0], py = xcur[(size_t)node*6+1], pz = xcur[(size_t)node*6+2];
        int beg = offs[node], end = offs[node+1];
        float accS = 0.f, av0 = 0.f, av1 = 0.f, av2 = 0.f;
        int idx = beg + wid;
        // 2-deep pipeline: src prefetched 2 ahead, position 1 ahead
        int srcA = 0, srcB = 0;
        float pex = 0.f, pey = 0.f, pez = 0.f;
        if (idx < end) srcA = srcSorted[idx];
        if (idx + 4 < end) srcB = srcSorted[idx + 4];
        if (idx < end) {
            const float* sp = xcur + (size_t)srcA*6;
            pex = sp[0]; pey = sp[1]; pez = sp[2];
        }
        for (; idx < end; idx += 4) {
            int srcU = srcA;
            float ex = pex - px, ey = pey - py, ez = pez - pz;
            srcA = srcB;
            if (idx + 8 < end) srcB = srcSorted[idx + 8];
            if (idx + 4 < end) {
                const float* sp = xcur + (size_t)srcA*6;
                pex = sp[0]; pey = sp[1]; pez = sp[2];
            }
            float el2 = ex*ex + ey*ey + ez*ez;
            if (el2 >= MAXR*MAXR) continue;   // wave-uniform skip: cut == 0
            // issue gathers early
            const float* vp = v1 + (size_t)srcU*192 + lane*3;
            float vv0 = vp[0], vv1 = vp[1], vv2 = vp[2];
            float sv = s1[(size_t)srcU*64 + lane];
            float elen = sqrtf(el2);
            float safe = fmaxf(elen, 1e-9f);
            float invSafe = 1.f/safe;
            float th = PI_F * safe * (1.f/MAXR);
            float s0, c0;
            __sincosf(th, &s0, &c0);
            // hid = silu( invSafe * sum_b sin((b+1)th)*(EFK*W1[b][lh]) + b1 )
            float hs = 0.f;
            {
                float sPrev = 0.f, sCur = s0, twoC = 2.f*c0;
                #pragma unroll
                for (int b = 0; b < NBD; ++b) {
                    hs = fmaf(sCur, w1e[b], hs);
                    float sN = fmaf(twoC, sCur, -sPrev);
                    sPrev = sCur; sCur = sN;
                }
            }
            float hid = silu_(fmaf(invSafe, hs, b1r));
            // (w1,w2) = hid_vec @ W2 : packed f32, 2-way accumulator split
            v2f accA = (v2f){0.f, 0.f}, accB = (v2f){0.f, 0.f};
            #pragma unroll
            for (int r = 0; r < RHD; r += 2) {
                float h0 = rdlane(hid, r), h1 = rdlane(hid, r+1);
                accA += ((v2f){h0, h0}) * wc[r];
                accB += ((v2f){h1, h1}) * wc[r+1];
            }
            v2f w12 = accA + accB;    // .x = w1, .y = w2
            float cut = s0*s0;        // 0.5*(1-cos(pi*u)) == sin^2(pi*elen/MAXR)
            float coef = SQRT3 * cut * invSafe;
            float ea0 = coef*ex, ea1 = coef*ey, ea2 = coef*ez;
            float dv = vv0*ea0 + vv1*ea1 + vv2*ea2;
            accS = fmaf(w12.y, dv, accS);
            float tt = w12.x * sv;
            av0 = fmaf(tt, ea0, av0); av1 = fmaf(tt, ea1, av1); av2 = fmaf(tt, ea2, av2);
        }
        red[wid][lane][0] = accS; red[wid][lane][1] = av0;
        red[wid][lane][2] = av1;  red[wid][lane][3] = av2;
        __syncthreads();
        if (wid == 0) {
            float rs = red[0][lane][0] + red[1][lane][0] + red[2][lane][0] + red[3][lane][0];
            aggS[(size_t)node*64 + lane] = rs*INVNN;
            float r0 = red[0][lane][1] + red[1][lane][1] + red[2][lane][1] + red[3][lane][1];
            float r1 = red[0][lane][2] + red[1][lane][2] + red[2][lane][2] + red[3][lane][2];
            float r2 = red[0][lane][3] + red[1][lane][3] + red[2][lane][3] + red[3][lane][3];
            float* ap = aggV + (size_t)node*192 + lane*3;
            ap[0] = r0*INVNN; ap[1] = r1*INVNN; ap[2] = r2*INVNN;
        }
        __syncthreads();
    }
}

// ---------------- out = lin2(agg) + sc(y) -> gating (persistent); gS/gV alias aggS/aggV ----------------
__global__ __launch_bounds__(256) void kOut(const float* __restrict__ ys, const float* __restrict__ yv,
        const float* __restrict__ aggS, const float* __restrict__ aggV, const int* __restrict__ attr,
        const float* __restrict__ L2s, const float* __restrict__ L2v,
        const float* __restrict__ Ts, const float* __restrict__ Tv,
        float* __restrict__ gS, float* __restrict__ gV, int n) {
    __shared__ float sL2s[64*128], sL2v[64*64];
    int t = threadIdx.x;
    for (int i = t; i < 64*128; i += 256) sL2s[i] = L2s[i];
    for (int i = t; i < 64*64;  i += 256) sL2v[i] = L2v[i];
    __syncthreads();
    int lane = t & 63;
    int wid = t >> 6;
    for (int node = blockIdx.x*4 + wid; node < n; node += gridDim.x*4) {
        int a = attr[node];
        const float* tS = Ts + (size_t)a*64*128;
        const float* tV = Tv + (size_t)a*64*64;
        float as_r = aggS[(size_t)node*64 + lane];
        float ys_r = ys[(size_t)node*64 + lane];
        const float* avp = aggV + (size_t)node*192 + lane*3;
        float av0 = avp[0], av1 = avp[1], av2 = avp[2];
        const float* yvp = yv + (size_t)node*192 + lane*3;
        float by0 = yvp[0], by1 = yvp[1], by2 = yvp[2];
        float oS0A=0.f,oS0B=0.f, oS1A=0.f,oS1B=0.f;
        float ov0A=0.f,ov0B=0.f, ov1A=0.f,ov1B=0.f, ov2A=0.f,ov2B=0.f;
        #pragma unroll 4
        for (int c = 0; c < 64; c += 2) {
            float asc0 = __shfl(as_r, c), ysc0 = __shfl(ys_r, c);
            float asc1 = __shfl(as_r, c+1), ysc1 = __shfl(ys_r, c+1);
            float a00 = __shfl(av0, c), a01 = __shfl(av1, c), a02 = __shfl(av2, c);
            float a10 = __shfl(av0, c+1), a11 = __shfl(av1, c+1), a12 = __shfl(av2, c+1);
            float b00 = __shfl(by0, c), b01 = __shfl(by1, c), b02 = __shfl(by2, c);
            float b10 = __shfl(by0, c+1), b11 = __shfl(by1, c+1), b12 = __shfl(by2, c+1);
            float lsa0 = sL2s[c*128 + lane], lsb0 = sL2s[c*128 + 64 + lane];
            float lsa1 = sL2s[(c+1)*128 + lane], lsb1 = sL2s[(c+1)*128 + 64 + lane];
            float lv0  = sL2v[c*64 + lane], lv1 = sL2v[(c+1)*64 + lane];
            float tsa0 = tS[c*128 + lane], tsb0 = tS[c*128 + 64 + lane];
            float tsa1 = tS[(c+1)*128 + lane], tsb1 = tS[(c+1)*128 + 64 + lane];
            float tv0  = tV[c*64 + lane], tv1 = tV[(c+1)*64 + lane];
            oS0A = fmaf(asc0, lsa0, fmaf(ysc0, tsa0, oS0A));
            oS0B = fmaf(asc1, lsa1, fmaf(ysc1, tsa1, oS0B));
            oS1A = fmaf(asc0, lsb0, fmaf(ysc0, tsb0, oS1A));
            oS1B = fmaf(asc1, lsb1, fmaf(ysc1, tsb1, oS1B));
            ov0A = fmaf(a00, lv0, fmaf(b00, tv0, ov0A));
            ov0B = fmaf(a10, lv1, fmaf(b10, tv1, ov0B));
            ov1A = fmaf(a01, lv0, fmaf(b01, tv0, ov1A));
            ov1B = fmaf(a11, lv1, fmaf(b11, tv1, ov1B));
            ov2A = fmaf(a02, lv0, fmaf(b02, tv0, ov2A));
            ov2B = fmaf(a12, lv1, fmaf(b12, tv1, ov2B));
        }
        float gs = silu_(oS0A + oS0B);
        float sg = sigm_(oS1A + oS1B);
        gS[(size_t)node*64 + lane] = gs;
        float* gp = gV + (size_t)node*192 + lane*3;
        gp[0] = sg*(ov0A+ov0B); gp[1] = sg*(ov1A+ov1B); gp[2] = sg*(ov2A+ov2B);
    }
}

// ---------------- combine (persistent) ----------------
__global__ __launch_bounds__(256) void kComb(const float* __restrict__ ys, const float* __restrict__ yv,
        const float* __restrict__ yolds, const float* __restrict__ yoldv,
        const float* __restrict__ gS, const float* __restrict__ gV,
        const float* __restrict__ siS, const float* __restrict__ siV, const float* __restrict__ Q,
        const float* __restrict__ hArr, const float* __restrict__ mArr, int li,
        float* __restrict__ newS, float* __restrict__ newV, float* __restrict__ xout, int n) {
    __shared__ float sSs[64*64], sSv[64*64];
    int t = threadIdx.x;
    for (int i = t; i < 4096; i += 256) { sSs[i] = siS[i]; sSv[i] = siV[i]; }
    __syncthreads();
    int lane = t & 63;
    int wid = t >> 6;
    float hh = hArr[li]; hh *= hh;
    float m = mArr[li];
    float q0 = Q[2*lane], q1 = Q[2*lane+1];
    for (int node = blockIdx.x*4 + wid; node < n; node += gridDim.x*4) {
        float ys_r = ys[(size_t)node*64 + lane];
        const float* yvp = yv + (size_t)node*192 + lane*3;
        float y0 = yvp[0], y1 = yvp[1], y2c = yvp[2];
        float q2sA=0.f,q2sB=0.f, qv0A=0.f,qv0B=0.f, qv1A=0.f,qv1B=0.f, qv2A=0.f,qv2B=0.f;
        #pragma unroll 8
        for (int c = 0; c < 64; c += 2) {
            float ysc0 = __shfl(ys_r, c), ysc1 = __shfl(ys_r, c+1);
            float b00 = __shfl(y0, c), b01 = __shfl(y1, c), b02 = __shfl(y2c, c);
            float b10 = __shfl(y0, c+1), b11 = __shfl(y1, c+1), b12 = __shfl(y2c, c+1);
            float ws0 = sSs[c*64 + lane], wv0 = sSv[c*64 + lane];
            float ws1 = sSs[(c+1)*64 + lane], wv1 = sSv[(c+1)*64 + lane];
            q2sA = fmaf(ysc0, ws0, q2sA); q2sB = fmaf(ysc1, ws1, q2sB);
            qv0A = fmaf(b00, wv0, qv0A);  qv0B = fmaf(b10, wv1, qv0B);
            qv1A = fmaf(b01, wv0, qv1A);  qv1B = fmaf(b11, wv1, qv1B);
            qv2A = fmaf(b02, wv0, qv2A);  qv2B = fmaf(b12, wv1, qv2B);
        }
        float q2s = q2sA+q2sB, qv0 = qv0A+qv0B, qv1 = qv1A+qv1B, qv2 = qv2A+qv2B;
        float yos = yolds[(size_t)node*64 + lane];
        const float* yop = yoldv + (size_t)node*192 + lane*3;
        float go = gS[(size_t)node*64 + lane];
        const float* gp = gV + (size_t)node*192 + lane*3;
        float ns  = 2.f*ys_r - yos   + hh*(m*go    + (m-1.f)*q2s);
        float nv0 = 2.f*y0  - yop[0] + hh*(m*gp[0] + (m-1.f)*qv0);
        float nv1 = 2.f*y1  - yop[1] + hh*(m*gp[1] + (m-1.f)*qv1);
        float nv2 = 2.f*y2c - yop[2] + hh*(m*gp[2] + (m-1.f)*qv2);
        newS[(size_t)node*64 + lane] = ns;
        float* np = newV + (size_t)node*192 + lane*3;
        np[0] = nv0; np[1] = nv1; np[2] = nv2;
        float p00 = nv0*q0, p01 = nv1*q0, p02 = nv2*q0;
        float p10 = nv0*q1, p11 = nv1*q1, p12 = nv2*q1;
        for (int o = 32; o > 0; o >>= 1) {
            p00 += __shfl_xor(p00, o); p01 += __shfl_xor(p01, o); p02 += __shfl_xor(p02, o);
            p10 += __shfl_xor(p10, o); p11 += __shfl_xor(p11, o); p12 += __shfl_xor(p12, o);
        }
        if (lane == 0) {
            float* xp = xout + (size_t)node*6;
            xp[0] = p00; xp[1] = p01; xp[2] = p02;
            xp[3] = p10; xp[4] = p11; xp[5] = p12;
        }
    }
}

extern "C" void kernel_launch(void* const* d_in, const int* in_sizes, int n_in,
                              void* d_out, int out_size, void* d_ws, size_t ws_size,
                              hipStream_t stream) {
    const float* x        = (const float*)d_in[0];
    const int*   nattr    = (const int*)  d_in[2];
    const int*   esrc     = (const int*)  d_in[3];
    const int*   edst     = (const int*)  d_in[4];
    const float* embT     = (const float*)d_in[5];
    const float* upM      = (const float*)d_in[6];
    const float* hArr     = (const float*)d_in[7];
    const float* mArr     = (const float*)d_in[8];
    const float* rW1      = (const float*)d_in[9];
    const float* rb1      = (const float*)d_in[10];
    const float* rW2      = (const float*)d_in[11];
    const float* l1s      = (const float*)d_in[12];
    const float* l1v      = (const float*)d_in[13];
    const float* l2s      = (const float*)d_in[14];
    const float* l2v      = (const float*)d_in[15];
    const float* scs      = (const float*)d_in[16];
    const float* scv      = (const float*)d_in[17];
    const float* sis      = (const float*)d_in[18];
    const float* siv      = (const float*)d_in[19];
    int n = in_sizes[0] / 6;
    int e = in_sizes[3];
    float* out = (float*)d_out;

    // ---- workspace carve ----
    float* w = (float*)d_ws;
    float* Q    = w; w += 128;
    float* yAs  = w; w += (size_t)n*64;
    float* yAv  = w; w += (size_t)n*192;
    float* yBs  = w; w += (size_t)n*64;
    float* yBv  = w; w += (size_t)n*192;
    float* s1   = w; w += (size_t)n*64;
    float* v1   = w; w += (size_t)n*192;
    float* aggS = w; w += (size_t)n*64;
    float* aggV = w; w += (size_t)n*192;
    float* xcur = w; w += (size_t)n*6;
    float* Ts   = w; w += (size_t)2*NATTR*64*128;
    float* Tv   = w; w += (size_t)2*NATTR*64*64;
    int* cnt       = (int*)w;
    int* offs      = cnt + n;
    int* cursor    = offs + (n + 1);
    int* srcSorted = cursor + n;
    size_t need = (size_t)((char*)(srcSorted + e) - (char*)d_ws);
    if (need > ws_size) {
        fprintf(stderr, "kernel_launch: ws too small (%zu > %zu)\n", need, ws_size);
        return;
    }

    const int AGG_GRID  = 1024;  // 4 blocks/CU (VGPR-limited at launch_bounds(256,4))
    const int LIN_GRID  = 1024;  // 32 KB LDS
    const int OUT_GRID  = 768;   // 48 KB LDS -> 3 blocks/CU
    const int COMB_GRID = 1024;

    kQ<<<1, 64, 0, stream>>>(upM, Q);
    kInit<<<(n*64 + 255)/256, 256, 0, stream>>>(x, Q, yAs, yAv, xcur, n);

    hipMemsetAsync(cnt, 0, (size_t)n*sizeof(int), stream);
    kHist<<<(e + 255)/256, 256, 0, stream>>>(edst, cnt, e);
    kScan<<<1, 1024, 0, stream>>>(cnt, offs, cursor, n);
    kScatter<<<(e + 255)/256, 256, 0, stream>>>(esrc, edst, cursor, srcSorted, e);

    kT<<<dim3(64, NATTR, 2), 192, 0, stream>>>(embT, scs, scv, Ts, Tv);

    for (int i = 0; i < 2; ++i) {
        const float* ysCur = (i == 0) ? yAs : yBs;
        const float* yvCur = (i == 0) ? yAv : yBv;
        const float* yoS = yAs;
        const float* yoV = yAv;
        float* nS = (i == 0) ? yBs : yAs;
        float* nV = (i == 0) ? yBv : yAv;
        float* xo = (i == 0) ? xcur : out;

        kLin1<<<LIN_GRID, 256, 0, stream>>>(ysCur, yvCur, l1s + i*4096, l1v + i*4096, s1, v1, n);
        kAgg<<<AGG_GRID, 256, 0, stream>>>(xcur, s1, v1, offs, srcSorted,
                                      rW1 + i*NBD*RHD, rb1 + i*RHD, rW2 + i*RHD*128,
                                      aggS, aggV, n);
        kOut<<<OUT_GRID, 256, 0, stream>>>(ysCur, yvCur, aggS, aggV, nattr,
                                      l2s + (size_t)i*64*128, l2v + (size_t)i*64*64,
                                      Ts + (size_t)i*NATTR*64*128, Tv + (size_t)i*NATTR*64*64,
                                      aggS, aggV, n);   // gating output aliases agg buffers
        kComb<<<COMB_GRID, 256, 0, stream>>>(ysCur, yvCur, yoS, yoV, aggS, aggV,
                                       sis + i*4096, siv + i*4096, Q, hArr, mArr, i,
                                       nS, nV, xo, n);
    }
}

// Round 4
// 968.977 us; speedup vs baseline: 1.5298x; 1.1747x over previous
//
#include <hip/hip_runtime.h>
#include <cstdio>
#include <cstdint>

#define CCH 64      // channels C
#define EMBD 32     // embedding dim
#define NBD 8       // num radial basis
#define RHD 32      // radial hidden
#define NATTR 100   // distinct node_attr values

static constexpr float MAXR    = 2.5f;
static constexpr float INVNN   = 0.17677669529663687f;  // 1/sqrt(32)
static constexpr float EFK     = 2.5298221281347035f;   // sqrt(2/2.5)*sqrt(8)
static constexpr float SQRT3   = 1.7320508075688772f;
static constexpr float PI_F    = 3.14159265358979323846f;

typedef float v2f __attribute__((ext_vector_type(2)));

__device__ __forceinline__ float sigm_(float x) { return 1.f / (1.f + __expf(-x)); }
__device__ __forceinline__ float silu_(float x) { return x / (1.f + __expf(-x)); }
__device__ __forceinline__ float rdlane(float v, int l) {
    return __uint_as_float(__builtin_amdgcn_readlane(__float_as_uint(v), l));
}
__device__ __forceinline__ float bf2f(unsigned short u) {
    return __uint_as_float(((unsigned)u) << 16);
}
__device__ __forceinline__ unsigned short f2bf(float f) {
    return (unsigned short)(__float_as_uint(f) >> 16);   // truncate: path damped by h^2
}

// ---------------- Q = polar factor of uplift_M (64x2) ----------------
__global__ void kQ(const float* M, float* Q) {
    int c = threadIdx.x;  // 64 threads = 1 wave
    float m0 = M[2*c], m1 = M[2*c+1];
    float a = m0*m0, b = m0*m1, d = m1*m1;
    for (int o = 32; o > 0; o >>= 1) {
        a += __shfl_xor(a, o); b += __shfl_xor(b, o); d += __shfl_xor(d, o);
    }
    float det = a*d - b*b;
    float s = sqrtf(det);
    float t = sqrtf(a + d + 2.f*s);
    float inv = 1.f / (s*t);
    float i00 = (d + s)*inv, i01 = -b*inv, i11 = (a + s)*inv;
    Q[2*c]   = m0*i00 + m1*i01;
    Q[2*c+1] = m0*i01 + m1*i11;
}

// ---------------- init: y0, xcur, and layer-0 lin1 (s1=0 analytically; v1 = yv@L1v) ----------------
__global__ __launch_bounds__(256) void kInitLin(const float* __restrict__ x, const float* __restrict__ Qg,
        const float* __restrict__ L1v,
        float* __restrict__ yAs, float* __restrict__ yAv, float* __restrict__ xcur,
        float* __restrict__ v1, int n) {
    __shared__ float sLv[64*64];
    int t = threadIdx.x;
    for (int i = t; i < 4096; i += 256) sLv[i] = L1v[i];
    __syncthreads();
    int lane = t & 63;
    int wid = t >> 6;
    float q0 = Qg[2*lane], q1 = Qg[2*lane+1];
    for (int node = blockIdx.x*4 + wid; node < n; node += gridDim.x*4) {
        const float* xr = x + (size_t)node*6;
        float x0 = xr[0], x1 = xr[1], x2 = xr[2], x3 = xr[3], x4 = xr[4], x5 = xr[5];
        float y0 = q0*x0 + q1*x3;
        float y1 = q0*x1 + q1*x4;
        float y2 = q0*x2 + q1*x5;
        float* yv = yAv + (size_t)node*192 + lane*3;
        yv[0] = y0; yv[1] = y1; yv[2] = y2;
        yAs[(size_t)node*64 + lane] = 0.f;
        if (lane < 6) xcur[(size_t)node*6 + lane] = xr[lane];
        float a0A=0.f, a0B=0.f, a1A=0.f, a1B=0.f, a2A=0.f, a2B=0.f;
        #pragma unroll 8
        for (int c = 0; c < 64; c += 2) {
            float b00 = __shfl(y0, c), b01 = __shfl(y1, c), b02 = __shfl(y2, c);
            float b10 = __shfl(y0, c+1), b11 = __shfl(y1, c+1), b12 = __shfl(y2, c+1);
            float wv0 = sLv[c*64 + lane], wv1 = sLv[(c+1)*64 + lane];
            a0A = fmaf(b00, wv0, a0A); a0B = fmaf(b10, wv1, a0B);
            a1A = fmaf(b01, wv0, a1A); a1B = fmaf(b11, wv1, a1B);
            a2A = fmaf(b02, wv0, a2A); a2B = fmaf(b12, wv1, a2B);
        }
        float* vp = v1 + (size_t)node*192 + lane*3;
        vp[0] = a0A + a0B; vp[1] = a1A + a1B; vp[2] = a2A + a2B;
    }
}

// ---------------- CSR build ----------------
__global__ void kHist(const int* dst, int* cnt, int e) {
    int i = blockIdx.x*blockDim.x + threadIdx.x;
    if (i < e) atomicAdd(&cnt[dst[i]], 1);
}

__global__ void kScan(const int* cnt, int* offs, int* cursor, int n) {
    __shared__ int part[1024];
    int t = threadIdx.x;
    int chunk = (n + 1023) >> 10;
    int lo = t*chunk, hi = min(lo + chunk, n);
    int s = 0;
    for (int i = lo; i < hi; ++i) s += cnt[i];
    part[t] = s;
    __syncthreads();
    for (int o = 1; o < 1024; o <<= 1) {
        int w = (t >= o) ? part[t - o] : 0;
        __syncthreads();
        part[t] += w;
        __syncthreads();
    }
    int run = part[t] - s;
    for (int i = lo; i < hi; ++i) {
        int cv = cnt[i];
        offs[i] = run; cursor[i] = run;
        run += cv;
    }
    if (t == 1023) offs[n] = part[1023];
}

__global__ void kScatter(const int* src, const int* dst, int* cursor,
                         int* srcSorted, int e) {
    int i = blockIdx.x*blockDim.x + threadIdx.x;
    if (i < e) {
        int p = atomicAdd(&cursor[dst[i]], 1);
        srcSorted[p] = src[i];
    }
}

// ---------------- T tables (bf16): loop attrs inside block; sc weights read once ----------------
__global__ __launch_bounds__(256) void kT2(const float* __restrict__ embT,
        const float* __restrict__ scs, const float* __restrict__ scv,
        unsigned short* __restrict__ Ts, unsigned short* __restrict__ Tv) {
    int c = blockIdx.x, l = blockIdx.y;
    __shared__ float sS[32*128], sV[32*64], sE[NATTR*EMBD];
    int t = threadIdx.x;
    const float* ps = scs + ((size_t)(l*CCH + c)*EMBD)*128;
    for (int i = t; i < 32*128; i += 256) sS[i] = ps[i];
    const float* pv = scv + ((size_t)(l*CCH + c)*EMBD)*64;
    for (int i = t; i < 32*64; i += 256) sV[i] = pv[i];
    for (int i = t; i < NATTR*EMBD; i += 256) sE[i] = embT[i];
    __syncthreads();
    if (t < 128) {
        for (int a = 0; a < NATTR; ++a) {
            float acc = 0.f;
            #pragma unroll
            for (int e = 0; e < EMBD; ++e) acc = fmaf(sE[a*EMBD + e], sS[e*128 + t], acc);
            Ts[(((size_t)l*NATTR + a)*CCH + c)*128 + t] = f2bf(acc);
        }
    } else if (t < 192) {
        int o = t - 128;
        for (int a = 0; a < NATTR; ++a) {
            float acc = 0.f;
            #pragma unroll
            for (int e = 0; e < EMBD; ++e) acc = fmaf(sE[a*EMBD + e], sV[e*64 + o], acc);
            Tv[(((size_t)l*NATTR + a)*CCH + c)*64 + o] = f2bf(acc);
        }
    }
}

// ---------------- lin1 (layer 1 only) ----------------
__global__ __launch_bounds__(256) void kLin1(const float* __restrict__ ys, const float* __restrict__ yv,
        const float* __restrict__ L1s, const float* __restrict__ L1v,
        float* __restrict__ s1, float* __restrict__ v1, int n) {
    __shared__ float sLs[64*64], sLv[64*64];
    int t = threadIdx.x;
    for (int i = t; i < 4096; i += 256) { sLs[i] = L1s[i]; sLv[i] = L1v[i]; }
    __syncthreads();
    int lane = t & 63;
    int wid = t >> 6;
    for (int node = blockIdx.x*4 + wid; node < n; node += gridDim.x*4) {
        float ys_r = ys[(size_t)node*64 + lane];
        const float* yvp = yv + (size_t)node*192 + lane*3;
        float y0 = yvp[0], y1 = yvp[1], y2 = yvp[2];
        float asA=0.f, asB=0.f, a0A=0.f, a0B=0.f, a1A=0.f, a1B=0.f, a2A=0.f, a2B=0.f;
        #pragma unroll 8
        for (int c = 0; c < 64; c += 2) {
            float ysc0 = __shfl(ys_r, c),  ysc1 = __shfl(ys_r, c+1);
            float b00 = __shfl(y0, c), b01 = __shfl(y1, c), b02 = __shfl(y2, c);
            float b10 = __shfl(y0, c+1), b11 = __shfl(y1, c+1), b12 = __shfl(y2, c+1);
            float ws0 = sLs[c*64 + lane], wv0 = sLv[c*64 + lane];
            float ws1 = sLs[(c+1)*64 + lane], wv1 = sLv[(c+1)*64 + lane];
            asA = fmaf(ysc0, ws0, asA); asB = fmaf(ysc1, ws1, asB);
            a0A = fmaf(b00, wv0, a0A);  a0B = fmaf(b10, wv1, a0B);
            a1A = fmaf(b01, wv0, a1A);  a1B = fmaf(b11, wv1, a1B);
            a2A = fmaf(b02, wv0, a2A);  a2B = fmaf(b12, wv1, a2B);
        }
        s1[(size_t)node*64 + lane] = asA + asB;
        float* vp = v1 + (size_t)node*192 + lane*3;
        vp[0] = a0A + a0B; vp[1] = a1A + a1B; vp[2] = a2A + a2B;
    }
}

// ---------------- aggregation: 4 waves/node, radial weights in registers ----------------
template<int WITHV>
__global__ __launch_bounds__(256) void kAgg(const float* __restrict__ xcur,
        const float* __restrict__ s1, const float* __restrict__ v1,
        const int* __restrict__ offs, const int* __restrict__ srcSorted,
        const float* __restrict__ rW1, const float* __restrict__ rb1, const float* __restrict__ rW2,
        float* __restrict__ aggS, float* __restrict__ aggV, int n) {
    __shared__ float red[4][64][4];
    int t = threadIdx.x;
    int lane = t & 63;
    int wid = t >> 6;
    int lh = lane & 31;
    float w1e[NBD];
    #pragma unroll
    for (int b = 0; b < NBD; ++b) w1e[b] = EFK * rW1[b*RHD + lh];
    float b1r = rb1[lh];
    v2f wcP[RHD];     // {W2[r][lane], W2[r][64+lane]}  (WITHV=1)
    float wc2[RHD];   // W2[r][64+lane]                 (WITHV=0)
    if (WITHV) {
        #pragma unroll
        for (int r = 0; r < RHD; ++r)
            wcP[r] = (v2f){ rW2[r*128 + lane], rW2[r*128 + 64 + lane] };
    } else {
        #pragma unroll
        for (int r = 0; r < RHD; ++r) wc2[r] = rW2[r*128 + 64 + lane];
    }

    for (int node = blockIdx.x; node < n; node += gridDim.x) {
        float px = xcur[(size_t)node*6+0], py = xcur[(size_t)node*6+1], pz = xcur[(size_t)node*6+2];
        int beg = offs[node], end = offs[node+1];
        float accS = 0.f, av0 = 0.f, av1 = 0.f, av2 = 0.f;
        int idx = beg + wid;
        int srcA = 0, srcB = 0;
        float pex = 0.f, pey = 0.f, pez = 0.f;
        if (idx < end) srcA = srcSorted[idx];
        if (idx + 4 < end) srcB = srcSorted[idx + 4];
        if (idx < end) {
            const float* sp = xcur + (size_t)srcA*6;
            pex = sp[0]; pey = sp[1]; pez = sp[2];
        }
        for (; idx < end; idx += 4) {
            int srcU = srcA;
            float ex = pex - px, ey = pey - py, ez = pez - pz;
            srcA = srcB;
            if (idx + 8 < end) srcB = srcSorted[idx + 8];
            if (idx + 4 < end) {
                const float* sp = xcur + (size_t)srcA*6;
                pex = sp[0]; pey = sp[1]; pez = sp[2];
            }
            float el2 = ex*ex + ey*ey + ez*ez;
            if (el2 >= MAXR*MAXR) continue;   // wave-uniform: cut == 0
            const float* vp = v1 + (size_t)srcU*192 + lane*3;
            float vv0 = vp[0], vv1 = vp[1], vv2 = vp[2];
            float sv = WITHV ? s1[(size_t)srcU*64 + lane] : 0.f;
            float elen = sqrtf(el2);
            float safe = fmaxf(elen, 1e-9f);
            float invSafe = 1.f/safe;
            float th = PI_F * safe * (1.f/MAXR);
            float s0, c0;
            __sincosf(th, &s0, &c0);
            float hs = 0.f;
            {
                float sPrev = 0.f, sCur = s0, twoC = 2.f*c0;
                #pragma unroll
                for (int b = 0; b < NBD; ++b) {
                    hs = fmaf(sCur, w1e[b], hs);
                    float sN = fmaf(twoC, sCur, -sPrev);
                    sPrev = sCur; sCur = sN;
                }
            }
            float hid = silu_(fmaf(invSafe, hs, b1r));
            float w1, w2;
            if (WITHV) {
                v2f accA = (v2f){0.f, 0.f}, accB = (v2f){0.f, 0.f};
                #pragma unroll
                for (int r = 0; r < RHD; r += 2) {
                    float h0 = rdlane(hid, r), h1 = rdlane(hid, r+1);
                    accA += ((v2f){h0, h0}) * wcP[r];
                    accB += ((v2f){h1, h1}) * wcP[r+1];
                }
                v2f w12 = accA + accB;
                w1 = w12.x; w2 = w12.y;
            } else {
                float a0=0.f, a1=0.f, a2=0.f, a3=0.f;
                #pragma unroll
                for (int r = 0; r < RHD; r += 4) {
                    a0 = fmaf(rdlane(hid, r),   wc2[r],   a0);
                    a1 = fmaf(rdlane(hid, r+1), wc2[r+1], a1);
                    a2 = fmaf(rdlane(hid, r+2), wc2[r+2], a2);
                    a3 = fmaf(rdlane(hid, r+3), wc2[r+3], a3);
                }
                w2 = (a0 + a1) + (a2 + a3); w1 = 0.f;
            }
            float cut = s0*s0;        // == sin^2(pi*elen/MAXR) == 0.5*(1-cos(pi*u))
            float coef = SQRT3 * cut * invSafe;
            float ea0 = coef*ex, ea1 = coef*ey, ea2 = coef*ez;
            float dv = vv0*ea0 + vv1*ea1 + vv2*ea2;
            accS = fmaf(w2, dv, accS);
            if (WITHV) {
                float tt = w1*sv;
                av0 = fmaf(tt, ea0, av0); av1 = fmaf(tt, ea1, av1); av2 = fmaf(tt, ea2, av2);
            }
        }
        red[wid][lane][0] = accS; red[wid][lane][1] = av0;
        red[wid][lane][2] = av1;  red[wid][lane][3] = av2;
        __syncthreads();
        if (wid == 0) {
            float rs = red[0][lane][0] + red[1][lane][0] + red[2][lane][0] + red[3][lane][0];
            aggS[(size_t)node*64 + lane] = rs*INVNN;
            float r0 = red[0][lane][1] + red[1][lane][1] + red[2][lane][1] + red[3][lane][1];
            float r1 = red[0][lane][2] + red[1][lane][2] + red[2][lane][2] + red[3][lane][2];
            float r2 = red[0][lane][3] + red[1][lane][3] + red[2][lane][3] + red[3][lane][3];
            float* ap = aggV + (size_t)node*192 + lane*3;
            ap[0] = r0*INVNN; ap[1] = r1*INVNN; ap[2] = r2*INVNN;
        }
        __syncthreads();
    }
}

// ---------------- fused out+gating+combine: 80 KB LDS, 2 blocks/CU ----------------
__global__ __launch_bounds__(256) void kOutComb(const float* __restrict__ ys, const float* __restrict__ yv,
        const float* __restrict__ yolds, const float* __restrict__ yoldv,
        const float* __restrict__ aggS, const float* __restrict__ aggV, const int* __restrict__ attr,
        const float* __restrict__ L2s, const float* __restrict__ L2v,
        const unsigned short* __restrict__ Ts, const unsigned short* __restrict__ Tv,
        const float* __restrict__ siS, const float* __restrict__ siV, const float* __restrict__ Qg,
        const float* __restrict__ hArr, const float* __restrict__ mArr, int li,
        float* __restrict__ newS, float* __restrict__ newV, float* __restrict__ xout,
        int writeY, int n) {
    __shared__ float sL2s[64*128], sL2v[64*64], sSs[64*64], sSv[64*64];
    int t = threadIdx.x;
    for (int i = t; i < 64*128; i += 256) sL2s[i] = L2s[i];
    for (int i = t; i < 64*64;  i += 256) { sL2v[i] = L2v[i]; sSs[i] = siS[i]; sSv[i] = siV[i]; }
    __syncthreads();
    int lane = t & 63;
    int wid = t >> 6;
    float hh = hArr[li]; hh *= hh;
    float m = mArr[li];
    float q0 = Qg[2*lane], q1 = Qg[2*lane+1];
    for (int node = blockIdx.x*4 + wid; node < n; node += gridDim.x*4) {
        int a = attr[node];
        const unsigned short* tS = Ts + (size_t)a*64*128;
        const unsigned short* tV = Tv + (size_t)a*64*64;
        float as_r = aggS[(size_t)node*64 + lane];
        float ys_r = ys[(size_t)node*64 + lane];
        const float* avp = aggV + (size_t)node*192 + lane*3;
        float av0 = avp[0], av1 = avp[1], av2 = avp[2];
        const float* yvp = yv + (size_t)node*192 + lane*3;
        float by0 = yvp[0], by1 = yvp[1], by2 = yvp[2];
        float oS0A=0.f,oS0B=0.f, oS1A=0.f,oS1B=0.f;
        float ov0A=0.f,ov0B=0.f, ov1A=0.f,ov1B=0.f, ov2A=0.f,ov2B=0.f;
        float q2sA=0.f,q2sB=0.f, qv0A=0.f,qv0B=0.f, qv1A=0.f,qv1B=0.f, qv2A=0.f,qv2B=0.f;
        #pragma unroll 4
        for (int c = 0; c < 64; c += 2) {
            float asc0 = __shfl(as_r, c),   asc1 = __shfl(as_r, c+1);
            float ysc0 = __shfl(ys_r, c),   ysc1 = __shfl(ys_r, c+1);
            float a00 = __shfl(av0, c), a01 = __shfl(av1, c), a02 = __shfl(av2, c);
            float a10 = __shfl(av0, c+1), a11 = __shfl(av1, c+1), a12 = __shfl(av2, c+1);
            float b00 = __shfl(by0, c), b01 = __shfl(by1, c), b02 = __shfl(by2, c);
            float b10 = __shfl(by0, c+1), b11 = __shfl(by1, c+1), b12 = __shfl(by2, c+1);
            float lsa0 = sL2s[c*128 + lane], lsb0 = sL2s[c*128 + 64 + lane];
            float lsa1 = sL2s[(c+1)*128 + lane], lsb1 = sL2s[(c+1)*128 + 64 + lane];
            float lv0  = sL2v[c*64 + lane], lv1 = sL2v[(c+1)*64 + lane];
            float tsa0 = bf2f(tS[c*128 + lane]), tsb0 = bf2f(tS[c*128 + 64 + lane]);
            float tsa1 = bf2f(tS[(c+1)*128 + lane]), tsb1 = bf2f(tS[(c+1)*128 + 64 + lane]);
            float tv0  = bf2f(tV[c*64 + lane]), tv1 = bf2f(tV[(c+1)*64 + lane]);
            float ws0 = sSs[c*64 + lane], ws1 = sSs[(c+1)*64 + lane];
            float wv0 = sSv[c*64 + lane], wv1 = sSv[(c+1)*64 + lane];
            oS0A = fmaf(asc0, lsa0, fmaf(ysc0, tsa0, oS0A));
            oS0B = fmaf(asc1, lsa1, fmaf(ysc1, tsa1, oS0B));
            oS1A = fmaf(asc0, lsb0, fmaf(ysc0, tsb0, oS1A));
            oS1B = fmaf(asc1, lsb1, fmaf(ysc1, tsb1, oS1B));
            ov0A = fmaf(a00, lv0, fmaf(b00, tv0, ov0A));
            ov0B = fmaf(a10, lv1, fmaf(b10, tv1, ov0B));
            ov1A = fmaf(a01, lv0, fmaf(b01, tv0, ov1A));
            ov1B = fmaf(a11, lv1, fmaf(b11, tv1, ov1B));
            ov2A = fmaf(a02, lv0, fmaf(b02, tv0, ov2A));
            ov2B = fmaf(a12, lv1, fmaf(b12, tv1, ov2B));
            q2sA = fmaf(ysc0, ws0, q2sA); q2sB = fmaf(ysc1, ws1, q2sB);
            qv0A = fmaf(b00, wv0, qv0A);  qv0B = fmaf(b10, wv1, qv0B);
            qv1A = fmaf(b01, wv0, qv1A);  qv1B = fmaf(b11, wv1, qv1B);
            qv2A = fmaf(b02, wv0, qv2A);  qv2B = fmaf(b12, wv1, qv2B);
        }
        float gs = silu_(oS0A + oS0B);
        float sg = sigm_(oS1A + oS1B);
        float gv0 = sg*(ov0A+ov0B), gv1 = sg*(ov1A+ov1B), gv2 = sg*(ov2A+ov2B);
        float q2s = q2sA+q2sB, qv0 = qv0A+qv0B, qv1 = qv1A+qv1B, qv2 = qv2A+qv2B;
        float yos = yolds[(size_t)node*64 + lane];
        const float* yop = yoldv + (size_t)node*192 + lane*3;
        float ns  = 2.f*ys_r - yos   + hh*(m*gs  + (m-1.f)*q2s);
        float nv0 = 2.f*by0 - yop[0] + hh*(m*gv0 + (m-1.f)*qv0);
        float nv1 = 2.f*by1 - yop[1] + hh*(m*gv1 + (m-1.f)*qv1);
        float nv2 = 2.f*by2 - yop[2] + hh*(m*gv2 + (m-1.f)*qv2);
        if (writeY) {
            newS[(size_t)node*64 + lane] = ns;
            float* np = newV + (size_t)node*192 + lane*3;
            np[0] = nv0; np[1] = nv1; np[2] = nv2;
        }
        float p00 = nv0*q0, p01 = nv1*q0, p02 = nv2*q0;
        float p10 = nv0*q1, p11 = nv1*q1, p12 = nv2*q1;
        for (int o = 32; o > 0; o >>= 1) {
            p00 += __shfl_xor(p00, o); p01 += __shfl_xor(p01, o); p02 += __shfl_xor(p02, o);
            p10 += __shfl_xor(p10, o); p11 += __shfl_xor(p11, o); p12 += __shfl_xor(p12, o);
        }
        if (lane == 0) {
            float* xp = xout + (size_t)node*6;
            xp[0] = p00; xp[1] = p01; xp[2] = p02;
            xp[3] = p10; xp[4] = p11; xp[5] = p12;
        }
    }
}

extern "C" void kernel_launch(void* const* d_in, const int* in_sizes, int n_in,
                              void* d_out, int out_size, void* d_ws, size_t ws_size,
                              hipStream_t stream) {
    const float* x        = (const float*)d_in[0];
    const int*   nattr    = (const int*)  d_in[2];
    const int*   esrc     = (const int*)  d_in[3];
    const int*   edst     = (const int*)  d_in[4];
    const float* embT     = (const float*)d_in[5];
    const float* upM      = (const float*)d_in[6];
    const float* hArr     = (const float*)d_in[7];
    const float* mArr     = (const float*)d_in[8];
    const float* rW1      = (const float*)d_in[9];
    const float* rb1      = (const float*)d_in[10];
    const float* rW2      = (const float*)d_in[11];
    const float* l1s      = (const float*)d_in[12];
    const float* l1v      = (const float*)d_in[13];
    const float* l2s      = (const float*)d_in[14];
    const float* l2v      = (const float*)d_in[15];
    const float* scs      = (const float*)d_in[16];
    const float* scv      = (const float*)d_in[17];
    const float* sis      = (const float*)d_in[18];
    const float* siv      = (const float*)d_in[19];
    int n = in_sizes[0] / 6;
    int e = in_sizes[3];
    float* out = (float*)d_out;

    // ---- workspace carve ----
    float* w = (float*)d_ws;
    float* Q    = w; w += 128;
    float* yAs  = w; w += (size_t)n*64;
    float* yAv  = w; w += (size_t)n*192;
    float* yBs  = w; w += (size_t)n*64;
    float* yBv  = w; w += (size_t)n*192;
    float* s1   = w; w += (size_t)n*64;
    float* v1   = w; w += (size_t)n*192;
    float* aggS = w; w += (size_t)n*64;
    float* aggV = w; w += (size_t)n*192;
    float* xcur = w; w += (size_t)n*6;
    unsigned short* Ts = (unsigned short*)w; w += (size_t)2*NATTR*64*128/2;
    unsigned short* Tv = (unsigned short*)w; w += (size_t)2*NATTR*64*64/2;
    int* cnt       = (int*)w;
    int* offs      = cnt + n;
    int* cursor    = offs + (n + 1);
    int* srcSorted = cursor + n;
    size_t need = (size_t)((char*)(srcSorted + e) - (char*)d_ws);
    if (need > ws_size) {
        fprintf(stderr, "kernel_launch: ws too small (%zu > %zu)\n", need, ws_size);
        return;
    }

    const int AGG_GRID  = 2048;  // 8 blocks/CU (VGPR<=64, LDS 4KB)
    const int OC_GRID   = 512;   // 2 blocks/CU (80 KB LDS)
    const int LIN_GRID  = 1024;

    kQ<<<1, 64, 0, stream>>>(upM, Q);
    hipMemsetAsync(cnt, 0, (size_t)n*sizeof(int), stream);
    kHist<<<(e + 255)/256, 256, 0, stream>>>(edst, cnt, e);
    kScan<<<1, 1024, 0, stream>>>(cnt, offs, cursor, n);
    kScatter<<<(e + 255)/256, 256, 0, stream>>>(esrc, edst, cursor, srcSorted, e);
    kT2<<<dim3(64, 2), 256, 0, stream>>>(embT, scs, scv, Ts, Tv);
    kInitLin<<<1280, 256, 0, stream>>>(x, Q, l1v, yAs, yAv, xcur, v1, n);

    // ---- layer 0 (s1 == 0 analytically) ----
    kAgg<0><<<AGG_GRID, 256, 0, stream>>>(xcur, s1, v1, offs, srcSorted,
                                  rW1, rb1, rW2, aggS, aggV, n);
    kOutComb<<<OC_GRID, 256, 0, stream>>>(yAs, yAv, yAs, yAv, aggS, aggV, nattr,
                                  l2s, l2v, Ts, Tv, sis, siv, Q, hArr, mArr, 0,
                                  yBs, yBv, xcur, 1, n);
    // ---- layer 1 ----
    kLin1<<<LIN_GRID, 256, 0, stream>>>(yBs, yBv, l1s + 4096, l1v + 4096, s1, v1, n);
    kAgg<1><<<AGG_GRID, 256, 0, stream>>>(xcur, s1, v1, offs, srcSorted,
                                  rW1 + NBD*RHD, rb1 + RHD, rW2 + RHD*128, aggS, aggV, n);
    kOutComb<<<OC_GRID, 256, 0, stream>>>(yBs, yBv, yAs, yAv, aggS, aggV, nattr,
                                  l2s + (size_t)64*128, l2v + (size_t)64*64,
                                  Ts + (size_t)NATTR*64*128, Tv + (size_t)NATTR*64*64,
                                  sis + 4096, siv + 4096, Q, hArr, mArr, 1,
                                  yAs, yAv, out, 0, n);
}

// Round 5
// 926.997 us; speedup vs baseline: 1.5991x; 1.0453x over previous
//
#include <hip/hip_runtime.h>
#include <cstdio>
#include <cstdint>

#define CCH 64      // channels C
#define EMBD 32     // embedding dim
#define NBD 8       // num radial basis
#define RHD 32      // radial hidden
#define NATTR 100   // distinct node_attr values

static constexpr float MAXR    = 2.5f;
static constexpr float INVNN   = 0.17677669529663687f;  // 1/sqrt(32)
static constexpr float EFK     = 2.5298221281347035f;   // sqrt(2/2.5)*sqrt(8)
static constexpr float SQRT3   = 1.7320508075688772f;
static constexpr float PI_F    = 3.14159265358979323846f;

typedef float v2f __attribute__((ext_vector_type(2)));

__device__ __forceinline__ float sigm_(float x) { return 1.f / (1.f + __expf(-x)); }
__device__ __forceinline__ float silu_(float x) { return x / (1.f + __expf(-x)); }
__device__ __forceinline__ float rdlane(float v, int l) {
    return __uint_as_float(__builtin_amdgcn_readlane(__float_as_uint(v), l));
}
__device__ __forceinline__ unsigned f2bfu(float f) {   // RNE bf16 in low 16
    unsigned u = __float_as_uint(f);
    return (u + 0x7FFF + ((u >> 16) & 1)) >> 16;
}
__device__ __forceinline__ unsigned pack2(float lo, float hi) {
    return f2bfu(lo) | (f2bfu(hi) << 16);
}
__device__ __forceinline__ float ulo(unsigned u) { return __uint_as_float(u << 16); }
__device__ __forceinline__ float uhi(unsigned u) { return __uint_as_float(u & 0xFFFF0000u); }

// ---------------- Q = polar factor of uplift_M (64x2) ----------------
__global__ void kQ(const float* M, float* Q) {
    int c = threadIdx.x;  // 64 threads = 1 wave
    float m0 = M[2*c], m1 = M[2*c+1];
    float a = m0*m0, b = m0*m1, d = m1*m1;
    for (int o = 32; o > 0; o >>= 1) {
        a += __shfl_xor(a, o); b += __shfl_xor(b, o); d += __shfl_xor(d, o);
    }
    float det = a*d - b*b;
    float s = sqrtf(det);
    float t = sqrtf(a + d + 2.f*s);
    float inv = 1.f / (s*t);
    float i00 = (d + s)*inv, i01 = -b*inv, i11 = (a + s)*inv;
    Q[2*c]   = m0*i00 + m1*i01;
    Q[2*c+1] = m0*i01 + m1*i11;
}

// ---------------- init: y0, pos4, layer-0 lin1 (s1=0; v1 = yv@L1v) packed bf16 ----------------
__global__ __launch_bounds__(256) void kInitLin(const float* __restrict__ x, const float* __restrict__ Qg,
        const float* __restrict__ L1v,
        float* __restrict__ yAs, float* __restrict__ yAv, float4* __restrict__ pos4,
        uint2* __restrict__ mv, int n) {
    __shared__ float sLv[64*64];
    int t = threadIdx.x;
    for (int i = t; i < 4096; i += 256) sLv[i] = L1v[i];
    __syncthreads();
    int lane = t & 63;
    int wid = t >> 6;
    float q0 = Qg[2*lane], q1 = Qg[2*lane+1];
    for (int node = blockIdx.x*4 + wid; node < n; node += gridDim.x*4) {
        const float* xr = x + (size_t)node*6;
        float x0 = xr[0], x1 = xr[1], x2 = xr[2], x3 = xr[3], x4 = xr[4], x5 = xr[5];
        float y0 = q0*x0 + q1*x3;
        float y1 = q0*x1 + q1*x4;
        float y2 = q0*x2 + q1*x5;
        float* yv = yAv + (size_t)node*192 + lane*3;
        yv[0] = y0; yv[1] = y1; yv[2] = y2;
        yAs[(size_t)node*64 + lane] = 0.f;
        if (lane == 0) pos4[node] = (float4){x0, x1, x2, 0.f};
        float a0A=0.f, a0B=0.f, a1A=0.f, a1B=0.f, a2A=0.f, a2B=0.f;
        #pragma unroll 8
        for (int c = 0; c < 64; c += 2) {
            float b00 = __shfl(y0, c), b01 = __shfl(y1, c), b02 = __shfl(y2, c);
            float b10 = __shfl(y0, c+1), b11 = __shfl(y1, c+1), b12 = __shfl(y2, c+1);
            float wv0 = sLv[c*64 + lane], wv1 = sLv[(c+1)*64 + lane];
            a0A = fmaf(b00, wv0, a0A); a0B = fmaf(b10, wv1, a0B);
            a1A = fmaf(b01, wv0, a1A); a1B = fmaf(b11, wv1, a1B);
            a2A = fmaf(b02, wv0, a2A); a2B = fmaf(b12, wv1, a2B);
        }
        mv[(size_t)node*64 + lane] =
            (uint2){ pack2(a0A+a0B, a1A+a1B), pack2(a2A+a2B, 0.f) };
    }
}

// ---------------- CSR build ----------------
__global__ void kHist(const int* dst, int* cnt, int e) {
    int i = blockIdx.x*blockDim.x + threadIdx.x;
    if (i < e) atomicAdd(&cnt[dst[i]], 1);
}

__global__ void kScan(const int* cnt, int* offs, int* cursor, int n) {
    __shared__ int part[1024];
    int t = threadIdx.x;
    int chunk = (n + 1023) >> 10;
    int lo = t*chunk, hi = min(lo + chunk, n);
    int s = 0;
    for (int i = lo; i < hi; ++i) s += cnt[i];
    part[t] = s;
    __syncthreads();
    for (int o = 1; o < 1024; o <<= 1) {
        int w = (t >= o) ? part[t - o] : 0;
        __syncthreads();
        part[t] += w;
        __syncthreads();
    }
    int run = part[t] - s;
    for (int i = lo; i < hi; ++i) {
        int cv = cnt[i];
        offs[i] = run; cursor[i] = run;
        run += cv;
    }
    if (t == 1023) offs[n] = part[1023];
}

__global__ void kScatter(const int* src, const int* dst, int* cursor,
                         int* srcSorted, int e) {
    int i = blockIdx.x*blockDim.x + threadIdx.x;
    if (i < e) {
        int p = atomicAdd(&cursor[dst[i]], 1);
        srcSorted[p] = src[i];
    }
}

// ---------------- T tables: bf16 c-pair packed; Tsp[a][cp][o]=(T[2cp][o],T[2cp+1][o]) ----------------
__global__ __launch_bounds__(256) void kT3(const float* __restrict__ embT,
        const float* __restrict__ scs, const float* __restrict__ scv,
        unsigned* __restrict__ Tsp, unsigned* __restrict__ Tvp) {
    int cp = blockIdx.x, l = blockIdx.y, ag = blockIdx.z;  // 32 x 2 x 5
    int c0 = 2*cp, c1 = c0 + 1;
    __shared__ float sS0[32*128], sS1[32*128], sV0[32*64], sV1[32*64], sE[20*EMBD];
    int t = threadIdx.x;
    const float* p0 = scs + ((size_t)(l*CCH + c0)*EMBD)*128;
    const float* p1 = scs + ((size_t)(l*CCH + c1)*EMBD)*128;
    for (int i = t; i < 32*128; i += 256) { sS0[i] = p0[i]; sS1[i] = p1[i]; }
    const float* q0 = scv + ((size_t)(l*CCH + c0)*EMBD)*64;
    const float* q1 = scv + ((size_t)(l*CCH + c1)*EMBD)*64;
    for (int i = t; i < 32*64; i += 256) { sV0[i] = q0[i]; sV1[i] = q1[i]; }
    const float* eb = embT + (size_t)ag*20*EMBD;
    for (int i = t; i < 20*EMBD; i += 256) sE[i] = eb[i];
    __syncthreads();
    if (t < 128) {
        int o = t;
        for (int a = 0; a < 20; ++a) {
            float acc0 = 0.f, acc1 = 0.f;
            #pragma unroll
            for (int e = 0; e < EMBD; ++e) {
                float ev = sE[a*EMBD + e];
                acc0 = fmaf(ev, sS0[e*128 + o], acc0);
                acc1 = fmaf(ev, sS1[e*128 + o], acc1);
            }
            int aa = ag*20 + a;
            Tsp[(((size_t)l*NATTR + aa)*32 + cp)*128 + o] = pack2(acc0, acc1);
        }
    } else if (t < 192) {
        int o = t - 128;
        for (int a = 0; a < 20; ++a) {
            float acc0 = 0.f, acc1 = 0.f;
            #pragma unroll
            for (int e = 0; e < EMBD; ++e) {
                float ev = sE[a*EMBD + e];
                acc0 = fmaf(ev, sV0[e*64 + o], acc0);
                acc1 = fmaf(ev, sV1[e*64 + o], acc1);
            }
            int aa = ag*20 + a;
            Tvp[(((size_t)l*NATTR + aa)*32 + cp)*64 + o] = pack2(acc0, acc1);
        }
    }
}

// ---------------- lin1 (layer 1): s1,v1 -> packed bf16 mv ----------------
__global__ __launch_bounds__(256) void kLin1(const float* __restrict__ ys, const float* __restrict__ yv,
        const float* __restrict__ L1s, const float* __restrict__ L1v,
        uint2* __restrict__ mv, int n) {
    __shared__ float sLs[64*64], sLv[64*64];
    int t = threadIdx.x;
    for (int i = t; i < 4096; i += 256) { sLs[i] = L1s[i]; sLv[i] = L1v[i]; }
    __syncthreads();
    int lane = t & 63;
    int wid = t >> 6;
    for (int node = blockIdx.x*4 + wid; node < n; node += gridDim.x*4) {
        float ys_r = ys[(size_t)node*64 + lane];
        const float* yvp = yv + (size_t)node*192 + lane*3;
        float y0 = yvp[0], y1 = yvp[1], y2 = yvp[2];
        float asA=0.f, asB=0.f, a0A=0.f, a0B=0.f, a1A=0.f, a1B=0.f, a2A=0.f, a2B=0.f;
        #pragma unroll 8
        for (int c = 0; c < 64; c += 2) {
            float ysc0 = __shfl(ys_r, c),  ysc1 = __shfl(ys_r, c+1);
            float b00 = __shfl(y0, c), b01 = __shfl(y1, c), b02 = __shfl(y2, c);
            float b10 = __shfl(y0, c+1), b11 = __shfl(y1, c+1), b12 = __shfl(y2, c+1);
            float ws0 = sLs[c*64 + lane], wv0 = sLv[c*64 + lane];
            float ws1 = sLs[(c+1)*64 + lane], wv1 = sLv[(c+1)*64 + lane];
            asA = fmaf(ysc0, ws0, asA); asB = fmaf(ysc1, ws1, asB);
            a0A = fmaf(b00, wv0, a0A);  a0B = fmaf(b10, wv1, a0B);
            a1A = fmaf(b01, wv0, a1A);  a1B = fmaf(b11, wv1, a1B);
            a2A = fmaf(b02, wv0, a2A);  a2B = fmaf(b12, wv1, a2B);
        }
        mv[(size_t)node*64 + lane] =
            (uint2){ pack2(a0A+a0B, a1A+a1B), pack2(a2A+a2B, asA+asB) };
    }
}

// ---------------- aggregation: 4 waves/node; pos4 + packed bf16 gather ----------------
template<int WITHV>
__global__ __launch_bounds__(256) void kAgg(const float4* __restrict__ pos4,
        const uint2* __restrict__ mv,
        const int* __restrict__ offs, const int* __restrict__ srcSorted,
        const float* __restrict__ rW1, const float* __restrict__ rb1, const float* __restrict__ rW2,
        float* __restrict__ aggS, float* __restrict__ aggV, int n) {
    __shared__ float red[4][64][4];
    int t = threadIdx.x;
    int lane = t & 63;
    int wid = t >> 6;
    int lh = lane & 31;
    float w1e[NBD];
    #pragma unroll
    for (int b = 0; b < NBD; ++b) w1e[b] = EFK * rW1[b*RHD + lh];
    float b1r = rb1[lh];
    v2f wcP[RHD];     // {W2[r][lane], W2[r][64+lane]}  (WITHV=1)
    float wc2[RHD];   // W2[r][64+lane]                 (WITHV=0)
    if (WITHV) {
        #pragma unroll
        for (int r = 0; r < RHD; ++r)
            wcP[r] = (v2f){ rW2[r*128 + lane], rW2[r*128 + 64 + lane] };
    } else {
        #pragma unroll
        for (int r = 0; r < RHD; ++r) wc2[r] = rW2[r*128 + 64 + lane];
    }

    for (int node = blockIdx.x; node < n; node += gridDim.x) {
        float4 pc = pos4[node];
        float px = pc.x, py = pc.y, pz = pc.z;
        int beg = offs[node], end = offs[node+1];
        float accS = 0.f, av0 = 0.f, av1 = 0.f, av2 = 0.f;
        int idx = beg + wid;
        int srcA = 0, srcB = 0;
        float4 pA = (float4){0.f,0.f,0.f,0.f};
        if (idx < end) srcA = srcSorted[idx];
        if (idx + 4 < end) srcB = srcSorted[idx + 4];
        if (idx < end) pA = pos4[srcA];
        for (; idx < end; idx += 4) {
            int srcU = srcA;
            float ex = pA.x - px, ey = pA.y - py, ez = pA.z - pz;
            srcA = srcB;
            if (idx + 8 < end) srcB = srcSorted[idx + 8];
            if (idx + 4 < end) pA = pos4[srcA];
            float el2 = ex*ex + ey*ey + ez*ez;
            if (el2 >= MAXR*MAXR) continue;   // wave-uniform: cut == 0
            uint2 mw = mv[(size_t)srcU*64 + lane];   // {v1x,v1y | v1z,s1} bf16
            float elen = sqrtf(el2);
            float safe = fmaxf(elen, 1e-9f);
            float invSafe = 1.f/safe;
            float th = PI_F * safe * (1.f/MAXR);
            float s0, c0;
            __sincosf(th, &s0, &c0);
            float hs = 0.f;
            {
                float sPrev = 0.f, sCur = s0, twoC = 2.f*c0;
                #pragma unroll
                for (int b = 0; b < NBD; ++b) {
                    hs = fmaf(sCur, w1e[b], hs);
                    float sN = fmaf(twoC, sCur, -sPrev);
                    sPrev = sCur; sCur = sN;
                }
            }
            float hid = silu_(fmaf(invSafe, hs, b1r));
            float w1, w2;
            if (WITHV) {
                v2f accA = (v2f){0.f, 0.f}, accB = (v2f){0.f, 0.f};
                #pragma unroll
                for (int r = 0; r < RHD; r += 2) {
                    float h0 = rdlane(hid, r), h1 = rdlane(hid, r+1);
                    accA += ((v2f){h0, h0}) * wcP[r];
                    accB += ((v2f){h1, h1}) * wcP[r+1];
                }
                v2f w12 = accA + accB;
                w1 = w12.x; w2 = w12.y;
            } else {
                float a0=0.f, a1=0.f, a2=0.f, a3=0.f;
                #pragma unroll
                for (int r = 0; r < RHD; r += 4) {
                    a0 = fmaf(rdlane(hid, r),   wc2[r],   a0);
                    a1 = fmaf(rdlane(hid, r+1), wc2[r+1], a1);
                    a2 = fmaf(rdlane(hid, r+2), wc2[r+2], a2);
                    a3 = fmaf(rdlane(hid, r+3), wc2[r+3], a3);
                }
                w2 = (a0 + a1) + (a2 + a3); w1 = 0.f;
            }
            float cut = s0*s0;        // == 0.5*(1-cos(pi*u))
            float coef = SQRT3 * cut * invSafe;
            float ea0 = coef*ex, ea1 = coef*ey, ea2 = coef*ez;
            float vv0 = ulo(mw.x), vv1 = uhi(mw.x), vv2 = ulo(mw.y);
            float dv = vv0*ea0 + vv1*ea1 + vv2*ea2;
            accS = fmaf(w2, dv, accS);
            if (WITHV) {
                float tt = w1 * uhi(mw.y);
                av0 = fmaf(tt, ea0, av0); av1 = fmaf(tt, ea1, av1); av2 = fmaf(tt, ea2, av2);
            }
        }
        red[wid][lane][0] = accS; red[wid][lane][1] = av0;
        red[wid][lane][2] = av1;  red[wid][lane][3] = av2;
        __syncthreads();
        if (wid == 0) {
            float rs = red[0][lane][0] + red[1][lane][0] + red[2][lane][0] + red[3][lane][0];
            aggS[(size_t)node*64 + lane] = rs*INVNN;
            float r0 = red[0][lane][1] + red[1][lane][1] + red[2][lane][1] + red[3][lane][1];
            float r1 = red[0][lane][2] + red[1][lane][2] + red[2][lane][2] + red[3][lane][2];
            float r2 = red[0][lane][3] + red[1][lane][3] + red[2][lane][3] + red[3][lane][3];
            float* ap = aggV + (size_t)node*192 + lane*3;
            ap[0] = r0*INVNN; ap[1] = r1*INVNN; ap[2] = r2*INVNN;
        }
        __syncthreads();
    }
}

// ---------------- fused out+gating+combine: bf16-pair weights in LDS (40 KB) ----------------
__global__ __launch_bounds__(256) void kOutComb(const float* __restrict__ ys, const float* __restrict__ yv,
        const float* __restrict__ yolds, const float* __restrict__ yoldv,
        const float* __restrict__ aggS, const float* __restrict__ aggV, const int* __restrict__ attr,
        const float* __restrict__ L2s, const float* __restrict__ L2v,
        const unsigned* __restrict__ Tsp, const unsigned* __restrict__ Tvp,
        const float* __restrict__ siS, const float* __restrict__ siV, const float* __restrict__ Qg,
        const float* __restrict__ hArr, const float* __restrict__ mArr, int li,
        float* __restrict__ newS, float* __restrict__ newV,
        float4* __restrict__ pos4out, float* __restrict__ xout6,
        int writeY, int n) {
    __shared__ unsigned pkL2s[32*128], pkL2v[32*64], pkSs[32*64], pkSv[32*64];
    int t = threadIdx.x;
    for (int i = t; i < 32*128; i += 256) {
        int cp = i >> 7, o = i & 127;
        pkL2s[i] = pack2(L2s[(2*cp)*128 + o], L2s[(2*cp+1)*128 + o]);
    }
    for (int i = t; i < 32*64; i += 256) {
        int cp = i >> 6, o = i & 63;
        pkL2v[i] = pack2(L2v[(2*cp)*64 + o], L2v[(2*cp+1)*64 + o]);
        pkSs[i]  = pack2(siS[(2*cp)*64 + o], siS[(2*cp+1)*64 + o]);
        pkSv[i]  = pack2(siV[(2*cp)*64 + o], siV[(2*cp+1)*64 + o]);
    }
    __syncthreads();
    int lane = t & 63;
    int wid = t >> 6;
    float hh = hArr[li]; hh *= hh;
    float m = mArr[li];
    float q0 = Qg[2*lane], q1 = Qg[2*lane+1];
    for (int node = blockIdx.x*4 + wid; node < n; node += gridDim.x*4) {
        int a = attr[node];
        const unsigned* tS = Tsp + (size_t)a*32*128;
        const unsigned* tV = Tvp + (size_t)a*32*64;
        float as_r = aggS[(size_t)node*64 + lane];
        float ys_r = ys[(size_t)node*64 + lane];
        const float* avp = aggV + (size_t)node*192 + lane*3;
        float av0 = avp[0], av1 = avp[1], av2 = avp[2];
        const float* yvp = yv + (size_t)node*192 + lane*3;
        float by0 = yvp[0], by1 = yvp[1], by2 = yvp[2];
        float oS0A=0.f,oS0B=0.f, oS1A=0.f,oS1B=0.f;
        float ov0A=0.f,ov0B=0.f, ov1A=0.f,ov1B=0.f, ov2A=0.f,ov2B=0.f;
        float q2sA=0.f,q2sB=0.f, qv0A=0.f,qv0B=0.f, qv1A=0.f,qv1B=0.f, qv2A=0.f,qv2B=0.f;
        #pragma unroll 4
        for (int cp = 0; cp < 32; ++cp) {
            int c = 2*cp;
            float asc0 = __shfl(as_r, c),   asc1 = __shfl(as_r, c+1);
            float ysc0 = __shfl(ys_r, c),   ysc1 = __shfl(ys_r, c+1);
            float a00 = __shfl(av0, c), a01 = __shfl(av1, c), a02 = __shfl(av2, c);
            float a10 = __shfl(av0, c+1), a11 = __shfl(av1, c+1), a12 = __shfl(av2, c+1);
            float b00 = __shfl(by0, c), b01 = __shfl(by1, c), b02 = __shfl(by2, c);
            float b10 = __shfl(by0, c+1), b11 = __shfl(by1, c+1), b12 = __shfl(by2, c+1);
            unsigned wA = pkL2s[cp*128 + lane];       // (lsa0, lsa1)
            unsigned wB = pkL2s[cp*128 + 64 + lane];  // (lsb0, lsb1)
            unsigned wV = pkL2v[cp*64 + lane];        // (lv0, lv1)
            unsigned wS = pkSs[cp*64 + lane];         // (ws0, ws1)
            unsigned wSv = pkSv[cp*64 + lane];        // (wv0, wv1)
            unsigned ts0 = tS[cp*128 + lane];         // (tsa0, tsa1)
            unsigned ts1 = tS[cp*128 + 64 + lane];    // (tsb0, tsb1)
            unsigned tvw = tV[cp*64 + lane];          // (tv0, tv1)
            float lsa0 = ulo(wA), lsa1 = uhi(wA);
            float lsb0 = ulo(wB), lsb1 = uhi(wB);
            float lv0 = ulo(wV), lv1 = uhi(wV);
            float ws0 = ulo(wS), ws1 = uhi(wS);
            float wv0 = ulo(wSv), wv1 = uhi(wSv);
            float tsa0 = ulo(ts0), tsa1 = uhi(ts0);
            float tsb0 = ulo(ts1), tsb1 = uhi(ts1);
            float tv0 = ulo(tvw), tv1 = uhi(tvw);
            oS0A = fmaf(asc0, lsa0, fmaf(ysc0, tsa0, oS0A));
            oS0B = fmaf(asc1, lsa1, fmaf(ysc1, tsa1, oS0B));
            oS1A = fmaf(asc0, lsb0, fmaf(ysc0, tsb0, oS1A));
            oS1B = fmaf(asc1, lsb1, fmaf(ysc1, tsb1, oS1B));
            ov0A = fmaf(a00, lv0, fmaf(b00, tv0, ov0A));
            ov0B = fmaf(a10, lv1, fmaf(b10, tv1, ov0B));
            ov1A = fmaf(a01, lv0, fmaf(b01, tv0, ov1A));
            ov1B = fmaf(a11, lv1, fmaf(b11, tv1, ov1B));
            ov2A = fmaf(a02, lv0, fmaf(b02, tv0, ov2A));
            ov2B = fmaf(a12, lv1, fmaf(b12, tv1, ov2B));
            q2sA = fmaf(ysc0, ws0, q2sA); q2sB = fmaf(ysc1, ws1, q2sB);
            qv0A = fmaf(b00, wv0, qv0A);  qv0B = fmaf(b10, wv1, qv0B);
            qv1A = fmaf(b01, wv0, qv1A);  qv1B = fmaf(b11, wv1, qv1B);
            qv2A = fmaf(b02, wv0, qv2A);  qv2B = fmaf(b12, wv1, qv2B);
        }
        float gs = silu_(oS0A + oS0B);
        float sg = sigm_(oS1A + oS1B);
        float gv0 = sg*(ov0A+ov0B), gv1 = sg*(ov1A+ov1B), gv2 = sg*(ov2A+ov2B);
        float q2s = q2sA+q2sB, qv0 = qv0A+qv0B, qv1 = qv1A+qv1B, qv2 = qv2A+qv2B;
        float yos = yolds[(size_t)node*64 + lane];
        const float* yop = yoldv + (size_t)node*192 + lane*3;
        float ns  = 2.f*ys_r - yos   + hh*(m*gs  + (m-1.f)*q2s);
        float nv0 = 2.f*by0 - yop[0] + hh*(m*gv0 + (m-1.f)*qv0);
        float nv1 = 2.f*by1 - yop[1] + hh*(m*gv1 + (m-1.f)*qv1);
        float nv2 = 2.f*by2 - yop[2] + hh*(m*gv2 + (m-1.f)*qv2);
        if (writeY) {
            newS[(size_t)node*64 + lane] = ns;
            float* np = newV + (size_t)node*192 + lane*3;
            np[0] = nv0; np[1] = nv1; np[2] = nv2;
        }
        float p00 = nv0*q0, p01 = nv1*q0, p02 = nv2*q0;
        float p10 = nv0*q1, p11 = nv1*q1, p12 = nv2*q1;
        for (int o = 32; o > 0; o >>= 1) {
            p00 += __shfl_xor(p00, o); p01 += __shfl_xor(p01, o); p02 += __shfl_xor(p02, o);
            p10 += __shfl_xor(p10, o); p11 += __shfl_xor(p11, o); p12 += __shfl_xor(p12, o);
        }
        if (lane == 0) {
            if (writeY) {
                pos4out[node] = (float4){p00, p01, p02, 0.f};
            } else {
                float* xp = xout6 + (size_t)node*6;
                xp[0] = p00; xp[1] = p01; xp[2] = p02;
                xp[3] = p10; xp[4] = p11; xp[5] = p12;
            }
        }
    }
}

extern "C" void kernel_launch(void* const* d_in, const int* in_sizes, int n_in,
                              void* d_out, int out_size, void* d_ws, size_t ws_size,
                              hipStream_t stream) {
    const float* x        = (const float*)d_in[0];
    const int*   nattr    = (const int*)  d_in[2];
    const int*   esrc     = (const int*)  d_in[3];
    const int*   edst     = (const int*)  d_in[4];
    const float* embT     = (const float*)d_in[5];
    const float* upM      = (const float*)d_in[6];
    const float* hArr     = (const float*)d_in[7];
    const float* mArr     = (const float*)d_in[8];
    const float* rW1      = (const float*)d_in[9];
    const float* rb1      = (const float*)d_in[10];
    const float* rW2      = (const float*)d_in[11];
    const float* l1s      = (const float*)d_in[12];
    const float* l1v      = (const float*)d_in[13];
    const float* l2s      = (const float*)d_in[14];
    const float* l2v      = (const float*)d_in[15];
    const float* scs      = (const float*)d_in[16];
    const float* scv      = (const float*)d_in[17];
    const float* sis      = (const float*)d_in[18];
    const float* siv      = (const float*)d_in[19];
    int n = in_sizes[0] / 6;
    int e = in_sizes[3];
    float* out = (float*)d_out;

    // ---- workspace carve ----
    float* w = (float*)d_ws;
    float* Q    = w; w += 128;
    float* yAs  = w; w += (size_t)n*64;
    float* yAv  = w; w += (size_t)n*192;
    float* yBs  = w; w += (size_t)n*64;
    float* yBv  = w; w += (size_t)n*192;
    float* aggS = w; w += (size_t)n*64;
    float* aggV = w; w += (size_t)n*192;
    float4* pos4 = (float4*)w; w += (size_t)n*4;
    uint2* mv    = (uint2*)w;  w += (size_t)n*128;   // n*64 uint2
    unsigned* Tsp = (unsigned*)w; w += (size_t)2*NATTR*32*128;
    unsigned* Tvp = (unsigned*)w; w += (size_t)2*NATTR*32*64;
    int* cnt       = (int*)w;
    int* offs      = cnt + n;
    int* cursor    = offs + (n + 1);
    int* srcSorted = cursor + n;
    size_t need = (size_t)((char*)(srcSorted + e) - (char*)d_ws);
    if (need > ws_size) {
        fprintf(stderr, "kernel_launch: ws too small (%zu > %zu)\n", need, ws_size);
        return;
    }

    const int AGG_GRID  = 2048;  // 8 blocks/CU, LDS 4 KB
    const int OC_GRID   = 1024;  // 4 blocks/CU (40 KB LDS)
    const int LIN_GRID  = 1024;

    kQ<<<1, 64, 0, stream>>>(upM, Q);
    hipMemsetAsync(cnt, 0, (size_t)n*sizeof(int), stream);
    kHist<<<(e + 255)/256, 256, 0, stream>>>(edst, cnt, e);
    kScan<<<1, 1024, 0, stream>>>(cnt, offs, cursor, n);
    kScatter<<<(e + 255)/256, 256, 0, stream>>>(esrc, edst, cursor, srcSorted, e);
    kT3<<<dim3(32, 2, 5), 256, 0, stream>>>(embT, scs, scv, Tsp, Tvp);
    kInitLin<<<1280, 256, 0, stream>>>(x, Q, l1v, yAs, yAv, pos4, mv, n);

    // ---- layer 0 (s1 == 0 analytically) ----
    kAgg<0><<<AGG_GRID, 256, 0, stream>>>(pos4, mv, offs, srcSorted,
                                  rW1, rb1, rW2, aggS, aggV, n);
    kOutComb<<<OC_GRID, 256, 0, stream>>>(yAs, yAv, yAs, yAv, aggS, aggV, nattr,
                                  l2s, l2v, Tsp, Tvp, sis, siv, Q, hArr, mArr, 0,
                                  yBs, yBv, pos4, out, 1, n);
    // ---- layer 1 ----
    kLin1<<<LIN_GRID, 256, 0, stream>>>(yBs, yBv, l1s + 4096, l1v + 4096, mv, n);
    kAgg<1><<<AGG_GRID, 256, 0, stream>>>(pos4, mv, offs, srcSorted,
                                  rW1 + NBD*RHD, rb1 + RHD, rW2 + RHD*128, aggS, aggV, n);
    kOutComb<<<OC_GRID, 256, 0, stream>>>(yBs, yBv, yAs, yAv, aggS, aggV, nattr,
                                  l2s + (size_t)64*128, l2v + (size_t)64*64,
                                  Tsp + (size_t)NATTR*32*128, Tvp + (size_t)NATTR*32*64,
                                  sis + 4096, siv + 4096, Q, hArr, mArr, 1,
                                  yAs, yAv, pos4, out, 0, n);
}

// Round 6
// 701.714 us; speedup vs baseline: 2.1125x; 1.3210x over previous
//
#include <hip/hip_runtime.h>
#include <cstdio>
#include <cstdint>

#define CCH 64      // channels C
#define EMBD 32     // embedding dim
#define NBD 8       // num radial basis
#define RHD 32      // radial hidden
#define NATTR 100   // distinct node_attr values
#define TBINS 64    // radial table intervals (65 sample points)

static constexpr float MAXR    = 2.5f;
static constexpr float INVNN   = 0.17677669529663687f;  // 1/sqrt(32)
static constexpr float EFK     = 2.5298221281347035f;   // sqrt(2/2.5)*sqrt(8)
static constexpr float SQRT3   = 1.7320508075688772f;
static constexpr float PI_F    = 3.14159265358979323846f;

typedef float v2f __attribute__((ext_vector_type(2)));

__device__ __forceinline__ float sigm_(float x) { return 1.f / (1.f + __expf(-x)); }
__device__ __forceinline__ float silu_(float x) { return x / (1.f + __expf(-x)); }
__device__ __forceinline__ unsigned f2bfu(float f) {   // RNE bf16 in low 16
    unsigned u = __float_as_uint(f);
    return (u + 0x7FFF + ((u >> 16) & 1)) >> 16;
}
__device__ __forceinline__ unsigned pack2(float lo, float hi) {
    return f2bfu(lo) | (f2bfu(hi) << 16);
}
__device__ __forceinline__ float ulo(unsigned u) { return __uint_as_float(u << 16); }
__device__ __forceinline__ float uhi(unsigned u) { return __uint_as_float(u & 0xFFFF0000u); }

// ---------------- Q = polar factor of uplift_M (64x2) ----------------
__global__ void kQ(const float* M, float* Q) {
    int c = threadIdx.x;  // 64 threads = 1 wave
    float m0 = M[2*c], m1 = M[2*c+1];
    float a = m0*m0, b = m0*m1, d = m1*m1;
    for (int o = 32; o > 0; o >>= 1) {
        a += __shfl_xor(a, o); b += __shfl_xor(b, o); d += __shfl_xor(d, o);
    }
    float det = a*d - b*b;
    float s = sqrtf(det);
    float t = sqrtf(a + d + 2.f*s);
    float inv = 1.f / (s*t);
    float i00 = (d + s)*inv, i01 = -b*inv, i11 = (a + s)*inv;
    Q[2*c]   = m0*i00 + m1*i01;
    Q[2*c+1] = m0*i01 + m1*i11;
}

// ---------------- radial table: tab[l][bin][c] = (w1[c], w2[c]) * sqrt3*cut/safe ----------------
__global__ void kRadTab(const float* __restrict__ rW1, const float* __restrict__ rb1,
                        const float* __restrict__ rW2, float2* __restrict__ tab) {
    int bin = blockIdx.x;       // 0..TBINS
    int l   = blockIdx.y;       // layer
    int lane = threadIdx.x;     // 64
    float r = bin * (MAXR / TBINS);
    float safe = fmaxf(r, 1e-9f);
    float invSafe = 1.f / safe;
    float th = PI_F * r * (1.f / MAXR);
    float s0, c0;
    __sincosf(th, &s0, &c0);
    __shared__ float hidS[RHD];
    if (lane < RHD) {
        float hs = rb1[l*RHD + lane];
        float sPrev = 0.f, sCur = s0, twoC = 2.f*c0;
        #pragma unroll
        for (int b = 0; b < NBD; ++b) {      // ef[b] = EFK*sin((b+1)th)*invSafe
            float efb = EFK * sCur * invSafe;
            hs = fmaf(efb, rW1[(l*NBD + b)*RHD + lane], hs);
            float sN = fmaf(twoC, sCur, -sPrev);
            sPrev = sCur; sCur = sN;
        }
        hidS[lane] = silu_(hs);
    }
    __syncthreads();
    float w1 = 0.f, w2 = 0.f;
    #pragma unroll
    for (int rr = 0; rr < RHD; ++rr) {
        float h = hidS[rr];
        w1 = fmaf(h, rW2[(l*RHD + rr)*128 + lane], w1);
        w2 = fmaf(h, rW2[(l*RHD + rr)*128 + 64 + lane], w2);
    }
    float cut = s0*s0;                       // == 0.5*(1-cos(pi*u))
    float coef = SQRT3 * cut * invSafe;
    tab[((size_t)l*(TBINS+1) + bin)*64 + lane] = (float2){w1*coef, w2*coef};
}

// ---------------- init: y0, pos4, layer-0 lin1 (s1=0; v1 = yv@L1v) packed bf16 ----------------
__global__ __launch_bounds__(256) void kInitLin(const float* __restrict__ x, const float* __restrict__ Qg,
        const float* __restrict__ L1v,
        float* __restrict__ yAs, float* __restrict__ yAv, float4* __restrict__ pos4,
        uint2* __restrict__ mv, int n) {
    __shared__ float sLv[64*64];
    int t = threadIdx.x;
    for (int i = t; i < 4096; i += 256) sLv[i] = L1v[i];
    __syncthreads();
    int lane = t & 63;
    int wid = t >> 6;
    float q0 = Qg[2*lane], q1 = Qg[2*lane+1];
    for (int node = blockIdx.x*4 + wid; node < n; node += gridDim.x*4) {
        const float* xr = x + (size_t)node*6;
        float x0 = xr[0], x1 = xr[1], x2 = xr[2], x3 = xr[3], x4 = xr[4], x5 = xr[5];
        float y0 = q0*x0 + q1*x3;
        float y1 = q0*x1 + q1*x4;
        float y2 = q0*x2 + q1*x5;
        float* yv = yAv + (size_t)node*192 + lane*3;
        yv[0] = y0; yv[1] = y1; yv[2] = y2;
        yAs[(size_t)node*64 + lane] = 0.f;
        if (lane == 0) pos4[node] = (float4){x0, x1, x2, 0.f};
        unsigned P01 = pack2(y0, y1);
        unsigned P2  = pack2(y2, 0.f);
        float a0A=0.f, a0B=0.f, a1A=0.f, a1B=0.f, a2A=0.f, a2B=0.f;
        #pragma unroll 8
        for (int c = 0; c < 64; c += 2) {
            unsigned u0 = __shfl(P01, c), v0 = __shfl(P2, c);
            unsigned u1 = __shfl(P01, c+1), v1u = __shfl(P2, c+1);
            float wv0 = sLv[c*64 + lane], wv1 = sLv[(c+1)*64 + lane];
            a0A = fmaf(ulo(u0), wv0, a0A); a0B = fmaf(ulo(u1), wv1, a0B);
            a1A = fmaf(uhi(u0), wv0, a1A); a1B = fmaf(uhi(u1), wv1, a1B);
            a2A = fmaf(ulo(v0), wv0, a2A); a2B = fmaf(ulo(v1u), wv1, a2B);
        }
        mv[(size_t)node*64 + lane] =
            (uint2){ pack2(a0A+a0B, a1A+a1B), pack2(a2A+a2B, 0.f) };
    }
}

// ---------------- CSR build ----------------
__global__ void kHist(const int* dst, int* cnt, int e) {
    int i = blockIdx.x*blockDim.x + threadIdx.x;
    if (i < e) atomicAdd(&cnt[dst[i]], 1);
}

__global__ void kScan(const int* cnt, int* offs, int* cursor, int n) {
    __shared__ int part[1024];
    int t = threadIdx.x;
    int chunk = (n + 1023) >> 10;
    int lo = t*chunk, hi = min(lo + chunk, n);
    int s = 0;
    for (int i = lo; i < hi; ++i) s += cnt[i];
    part[t] = s;
    __syncthreads();
    for (int o = 1; o < 1024; o <<= 1) {
        int w = (t >= o) ? part[t - o] : 0;
        __syncthreads();
        part[t] += w;
        __syncthreads();
    }
    int run = part[t] - s;
    for (int i = lo; i < hi; ++i) {
        int cv = cnt[i];
        offs[i] = run; cursor[i] = run;
        run += cv;
    }
    if (t == 1023) offs[n] = part[1023];
}

__global__ void kScatter(const int* src, const int* dst, int* cursor,
                         int* srcSorted, int e) {
    int i = blockIdx.x*blockDim.x + threadIdx.x;
    if (i < e) {
        int p = atomicAdd(&cursor[dst[i]], 1);
        srcSorted[p] = src[i];
    }
}

// ---------------- T tables: bf16 c-pair packed ----------------
__global__ __launch_bounds__(256) void kT3(const float* __restrict__ embT,
        const float* __restrict__ scs, const float* __restrict__ scv,
        unsigned* __restrict__ Tsp, unsigned* __restrict__ Tvp) {
    int cp = blockIdx.x, l = blockIdx.y, ag = blockIdx.z;  // 32 x 2 x 5
    int c0 = 2*cp, c1 = c0 + 1;
    __shared__ float sS0[32*128], sS1[32*128], sV0[32*64], sV1[32*64], sE[20*EMBD];
    int t = threadIdx.x;
    const float* p0 = scs + ((size_t)(l*CCH + c0)*EMBD)*128;
    const float* p1 = scs + ((size_t)(l*CCH + c1)*EMBD)*128;
    for (int i = t; i < 32*128; i += 256) { sS0[i] = p0[i]; sS1[i] = p1[i]; }
    const float* q0 = scv + ((size_t)(l*CCH + c0)*EMBD)*64;
    const float* q1 = scv + ((size_t)(l*CCH + c1)*EMBD)*64;
    for (int i = t; i < 32*64; i += 256) { sV0[i] = q0[i]; sV1[i] = q1[i]; }
    const float* eb = embT + (size_t)ag*20*EMBD;
    for (int i = t; i < 20*EMBD; i += 256) sE[i] = eb[i];
    __syncthreads();
    if (t < 128) {
        int o = t;
        for (int a = 0; a < 20; ++a) {
            float acc0 = 0.f, acc1 = 0.f;
            #pragma unroll
            for (int e = 0; e < EMBD; ++e) {
                float ev = sE[a*EMBD + e];
                acc0 = fmaf(ev, sS0[e*128 + o], acc0);
                acc1 = fmaf(ev, sS1[e*128 + o], acc1);
            }
            int aa = ag*20 + a;
            Tsp[(((size_t)l*NATTR + aa)*32 + cp)*128 + o] = pack2(acc0, acc1);
        }
    } else if (t < 192) {
        int o = t - 128;
        for (int a = 0; a < 20; ++a) {
            float acc0 = 0.f, acc1 = 0.f;
            #pragma unroll
            for (int e = 0; e < EMBD; ++e) {
                float ev = sE[a*EMBD + e];
                acc0 = fmaf(ev, sV0[e*64 + o], acc0);
                acc1 = fmaf(ev, sV1[e*64 + o], acc1);
            }
            int aa = ag*20 + a;
            Tvp[(((size_t)l*NATTR + aa)*32 + cp)*64 + o] = pack2(acc0, acc1);
        }
    }
}

// ---------------- lin1 (layer 1): s1,v1 -> packed bf16 mv ----------------
__global__ __launch_bounds__(256) void kLin1(const float* __restrict__ ys, const float* __restrict__ yv,
        const float* __restrict__ L1s, const float* __restrict__ L1v,
        uint2* __restrict__ mv, int n) {
    __shared__ float sLs[64*64], sLv[64*64];
    int t = threadIdx.x;
    for (int i = t; i < 4096; i += 256) { sLs[i] = L1s[i]; sLv[i] = L1v[i]; }
    __syncthreads();
    int lane = t & 63;
    int wid = t >> 6;
    for (int node = blockIdx.x*4 + wid; node < n; node += gridDim.x*4) {
        float ys_r = ys[(size_t)node*64 + lane];
        const float* yvp = yv + (size_t)node*192 + lane*3;
        float y0 = yvp[0], y1 = yvp[1], y2 = yvp[2];
        unsigned P01 = pack2(y0, y1);
        unsigned P2s = pack2(y2, ys_r);
        float asA=0.f, asB=0.f, a0A=0.f, a0B=0.f, a1A=0.f, a1B=0.f, a2A=0.f, a2B=0.f;
        #pragma unroll 8
        for (int c = 0; c < 64; c += 2) {
            unsigned u0 = __shfl(P01, c),  v0 = __shfl(P2s, c);
            unsigned u1 = __shfl(P01, c+1), v1u = __shfl(P2s, c+1);
            float ws0 = sLs[c*64 + lane], wv0 = sLv[c*64 + lane];
            float ws1 = sLs[(c+1)*64 + lane], wv1 = sLv[(c+1)*64 + lane];
            asA = fmaf(uhi(v0), ws0, asA); asB = fmaf(uhi(v1u), ws1, asB);
            a0A = fmaf(ulo(u0), wv0, a0A); a0B = fmaf(ulo(u1), wv1, a0B);
            a1A = fmaf(uhi(u0), wv0, a1A); a1B = fmaf(uhi(u1), wv1, a1B);
            a2A = fmaf(ulo(v0), wv0, a2A); a2B = fmaf(ulo(v1u), wv1, a2B);
        }
        mv[(size_t)node*64 + lane] =
            (uint2){ pack2(a0A+a0B, a1A+a1B), pack2(a2A+a2B, asA+asB) };
    }
}

// ---------------- aggregation: radial MLP replaced by LDS table lerp ----------------
template<int WITHV>
__global__ __launch_bounds__(256) void kAgg(const float4* __restrict__ pos4,
        const uint2* __restrict__ mv,
        const int* __restrict__ offs, const int* __restrict__ srcSorted,
        const float2* __restrict__ tabG,
        float* __restrict__ aggS, float* __restrict__ aggV, int n) {
    __shared__ float2 tab[(TBINS+1)*64];   // 33280 B
    __shared__ float red[4][64][4];
    int t = threadIdx.x;
    for (int i = t; i < (TBINS+1)*64; i += 256) tab[i] = tabG[i];
    __syncthreads();
    int lane = t & 63;
    int wid = t >> 6;

    for (int node = blockIdx.x; node < n; node += gridDim.x) {
        float4 pc = pos4[node];
        float px = pc.x, py = pc.y, pz = pc.z;
        int beg = offs[node], end = offs[node+1];
        float accS = 0.f, av0 = 0.f, av1 = 0.f, av2 = 0.f;
        int idx = beg + wid;
        int srcA = 0, srcB = 0;
        float4 pA = (float4){0.f,0.f,0.f,0.f};
        if (idx < end) srcA = srcSorted[idx];
        if (idx + 4 < end) srcB = srcSorted[idx + 4];
        if (idx < end) pA = pos4[srcA];
        for (; idx < end; idx += 4) {
            int srcU = srcA;
            float ex = pA.x - px, ey = pA.y - py, ez = pA.z - pz;
            srcA = srcB;
            if (idx + 8 < end) srcB = srcSorted[idx + 8];
            if (idx + 4 < end) pA = pos4[srcA];
            float el2 = ex*ex + ey*ey + ez*ez;
            if (el2 >= MAXR*MAXR) continue;   // wave-uniform: cut == 0
            uint2 mw = mv[(size_t)srcU*64 + lane];   // {v1x,v1y | v1z,s1} bf16
            float elen = sqrtf(el2);
            float u = elen * ((float)TBINS / MAXR);  // < TBINS
            int i0 = (int)u;
            float fr = u - (float)i0;
            float2 t0 = tab[i0*64 + lane];
            float2 t1 = tab[i0*64 + 64 + lane];
            float w1 = fmaf(fr, t1.x - t0.x, t0.x);  // w1 * sqrt3*cut/safe
            float w2 = fmaf(fr, t1.y - t0.y, t0.y);  // w2 * sqrt3*cut/safe
            float vv0 = ulo(mw.x), vv1 = uhi(mw.x), vv2 = ulo(mw.y);
            float dv = vv0*ex + vv1*ey + vv2*ez;
            accS = fmaf(w2, dv, accS);
            if (WITHV) {
                float tt = w1 * uhi(mw.y);
                av0 = fmaf(tt, ex, av0); av1 = fmaf(tt, ey, av1); av2 = fmaf(tt, ez, av2);
            }
        }
        red[wid][lane][0] = accS; red[wid][lane][1] = av0;
        red[wid][lane][2] = av1;  red[wid][lane][3] = av2;
        __syncthreads();
        if (wid == 0) {
            float rs = red[0][lane][0] + red[1][lane][0] + red[2][lane][0] + red[3][lane][0];
            aggS[(size_t)node*64 + lane] = rs*INVNN;
            float r0 = red[0][lane][1] + red[1][lane][1] + red[2][lane][1] + red[3][lane][1];
            float r1 = red[0][lane][2] + red[1][lane][2] + red[2][lane][2] + red[3][lane][2];
            float r2 = red[0][lane][3] + red[1][lane][3] + red[2][lane][3] + red[3][lane][3];
            float* ap = aggV + (size_t)node*192 + lane*3;
            ap[0] = r0*INVNN; ap[1] = r1*INVNN; ap[2] = r2*INVNN;
        }
        __syncthreads();
    }
}

// ---------------- fused out+gating+combine: bf16-pair weights in LDS, packed shfl ----------------
__global__ __launch_bounds__(256) void kOutComb(const float* __restrict__ ys, const float* __restrict__ yv,
        const float* __restrict__ yolds, const float* __restrict__ yoldv,
        const float* __restrict__ aggS, const float* __restrict__ aggV, const int* __restrict__ attr,
        const float* __restrict__ L2s, const float* __restrict__ L2v,
        const unsigned* __restrict__ Tsp, const unsigned* __restrict__ Tvp,
        const float* __restrict__ siS, const float* __restrict__ siV, const float* __restrict__ Qg,
        const float* __restrict__ hArr, const float* __restrict__ mArr, int li,
        float* __restrict__ newS, float* __restrict__ newV,
        float4* __restrict__ pos4out, float* __restrict__ xout6,
        int writeY, int n) {
    __shared__ unsigned pkL2s[32*128], pkL2v[32*64], pkSs[32*64], pkSv[32*64];
    int t = threadIdx.x;
    for (int i = t; i < 32*128; i += 256) {
        int cp = i >> 7, o = i & 127;
        pkL2s[i] = pack2(L2s[(2*cp)*128 + o], L2s[(2*cp+1)*128 + o]);
    }
    for (int i = t; i < 32*64; i += 256) {
        int cp = i >> 6, o = i & 63;
        pkL2v[i] = pack2(L2v[(2*cp)*64 + o], L2v[(2*cp+1)*64 + o]);
        pkSs[i]  = pack2(siS[(2*cp)*64 + o], siS[(2*cp+1)*64 + o]);
        pkSv[i]  = pack2(siV[(2*cp)*64 + o], siV[(2*cp+1)*64 + o]);
    }
    __syncthreads();
    int lane = t & 63;
    int wid = t >> 6;
    float hh = hArr[li]; hh *= hh;
    float m = mArr[li];
    float q0 = Qg[2*lane], q1 = Qg[2*lane+1];
    for (int node = blockIdx.x*4 + wid; node < n; node += gridDim.x*4) {
        int a = attr[node];
        const unsigned* tS = Tsp + (size_t)a*32*128;
        const unsigned* tV = Tvp + (size_t)a*32*64;
        float as_r = aggS[(size_t)node*64 + lane];
        float ys_r = ys[(size_t)node*64 + lane];
        const float* avp = aggV + (size_t)node*192 + lane*3;
        float av0 = avp[0], av1 = avp[1], av2 = avp[2];
        const float* yvp = yv + (size_t)node*192 + lane*3;
        float by0 = yvp[0], by1 = yvp[1], by2 = yvp[2];
        // packed bf16 broadcasts (all consumers are h^2-damped)
        unsigned PAY = pack2(as_r, ys_r);
        unsigned P0 = pack2(av0, by0);
        unsigned P1 = pack2(av1, by1);
        unsigned P2 = pack2(av2, by2);
        float oS0A=0.f,oS0B=0.f, oS1A=0.f,oS1B=0.f;
        float ov0A=0.f,ov0B=0.f, ov1A=0.f,ov1B=0.f, ov2A=0.f,ov2B=0.f;
        float q2sA=0.f,q2sB=0.f, qv0A=0.f,qv0B=0.f, qv1A=0.f,qv1B=0.f, qv2A=0.f,qv2B=0.f;
        #pragma unroll 4
        for (int cp = 0; cp < 32; ++cp) {
            int c = 2*cp;
            unsigned sAY0 = __shfl(PAY, c), sAY1 = __shfl(PAY, c+1);
            unsigned s00 = __shfl(P0, c), s01 = __shfl(P0, c+1);
            unsigned s10 = __shfl(P1, c), s11 = __shfl(P1, c+1);
            unsigned s20 = __shfl(P2, c), s21 = __shfl(P2, c+1);
            float asc0 = ulo(sAY0), ysc0 = uhi(sAY0);
            float asc1 = ulo(sAY1), ysc1 = uhi(sAY1);
            float a00 = ulo(s00), b00 = uhi(s00);
            float a10 = ulo(s01), b10 = uhi(s01);
            float a01 = ulo(s10), b01 = uhi(s10);
            float a11 = ulo(s11), b11 = uhi(s11);
            float a02 = ulo(s20), b02 = uhi(s20);
            float a12 = ulo(s21), b12 = uhi(s21);
            unsigned wA = pkL2s[cp*128 + lane];
            unsigned wB = pkL2s[cp*128 + 64 + lane];
            unsigned wV = pkL2v[cp*64 + lane];
            unsigned wS = pkSs[cp*64 + lane];
            unsigned wSv = pkSv[cp*64 + lane];
            unsigned ts0 = tS[cp*128 + lane];
            unsigned ts1 = tS[cp*128 + 64 + lane];
            unsigned tvw = tV[cp*64 + lane];
            float lsa0 = ulo(wA), lsa1 = uhi(wA);
            float lsb0 = ulo(wB), lsb1 = uhi(wB);
            float lv0 = ulo(wV), lv1 = uhi(wV);
            float ws0 = ulo(wS), ws1 = uhi(wS);
            float wv0 = ulo(wSv), wv1 = uhi(wSv);
            float tsa0 = ulo(ts0), tsa1 = uhi(ts0);
            float tsb0 = ulo(ts1), tsb1 = uhi(ts1);
            float tv0 = ulo(tvw), tv1 = uhi(tvw);
            oS0A = fmaf(asc0, lsa0, fmaf(ysc0, tsa0, oS0A));
            oS0B = fmaf(asc1, lsa1, fmaf(ysc1, tsa1, oS0B));
            oS1A = fmaf(asc0, lsb0, fmaf(ysc0, tsb0, oS1A));
            oS1B = fmaf(asc1, lsb1, fmaf(ysc1, tsb1, oS1B));
            ov0A = fmaf(a00, lv0, fmaf(b00, tv0, ov0A));
            ov0B = fmaf(a10, lv1, fmaf(b10, tv1, ov0B));
            ov1A = fmaf(a01, lv0, fmaf(b01, tv0, ov1A));
            ov1B = fmaf(a11, lv1, fmaf(b11, tv1, ov1B));
            ov2A = fmaf(a02, lv0, fmaf(b02, tv0, ov2A));
            ov2B = fmaf(a12, lv1, fmaf(b12, tv1, ov2B));
            q2sA = fmaf(ysc0, ws0, q2sA); q2sB = fmaf(ysc1, ws1, q2sB);
            qv0A = fmaf(b00, wv0, qv0A);  qv0B = fmaf(b10, wv1, qv0B);
            qv1A = fmaf(b01, wv0, qv1A);  qv1B = fmaf(b11, wv1, qv1B);
            qv2A = fmaf(b02, wv0, qv2A);  qv2B = fmaf(b12, wv1, qv2B);
        }
        float gs = silu_(oS0A + oS0B);
        float sg = sigm_(oS1A + oS1B);
        float gv0 = sg*(ov0A+ov0B), gv1 = sg*(ov1A+ov1B), gv2 = sg*(ov2A+ov2B);
        float q2s = q2sA+q2sB, qv0 = qv0A+qv0B, qv1 = qv1A+qv1B, qv2 = qv2A+qv2B;
        float yos = yolds[(size_t)node*64 + lane];
        const float* yop = yoldv + (size_t)node*192 + lane*3;
        float ns  = 2.f*ys_r - yos   + hh*(m*gs  + (m-1.f)*q2s);
        float nv0 = 2.f*by0 - yop[0] + hh*(m*gv0 + (m-1.f)*qv0);
        float nv1 = 2.f*by1 - yop[1] + hh*(m*gv1 + (m-1.f)*qv1);
        float nv2 = 2.f*by2 - yop[2] + hh*(m*gv2 + (m-1.f)*qv2);
        if (writeY) {
            newS[(size_t)node*64 + lane] = ns;
            float* np = newV + (size_t)node*192 + lane*3;
            np[0] = nv0; np[1] = nv1; np[2] = nv2;
        }
        float p00 = nv0*q0, p01 = nv1*q0, p02 = nv2*q0;
        float p10 = nv0*q1, p11 = nv1*q1, p12 = nv2*q1;
        for (int o = 32; o > 0; o >>= 1) {
            p00 += __shfl_xor(p00, o); p01 += __shfl_xor(p01, o); p02 += __shfl_xor(p02, o);
            p10 += __shfl_xor(p10, o); p11 += __shfl_xor(p11, o); p12 += __shfl_xor(p12, o);
        }
        if (lane == 0) {
            if (writeY) {
                pos4out[node] = (float4){p00, p01, p02, 0.f};
            } else {
                float* xp = xout6 + (size_t)node*6;
                xp[0] = p00; xp[1] = p01; xp[2] = p02;
                xp[3] = p10; xp[4] = p11; xp[5] = p12;
            }
        }
    }
}

extern "C" void kernel_launch(void* const* d_in, const int* in_sizes, int n_in,
                              void* d_out, int out_size, void* d_ws, size_t ws_size,
                              hipStream_t stream) {
    const float* x        = (const float*)d_in[0];
    const int*   nattr    = (const int*)  d_in[2];
    const int*   esrc     = (const int*)  d_in[3];
    const int*   edst     = (const int*)  d_in[4];
    const float* embT     = (const float*)d_in[5];
    const float* upM      = (const float*)d_in[6];
    const float* hArr     = (const float*)d_in[7];
    const float* mArr     = (const float*)d_in[8];
    const float* rW1      = (const float*)d_in[9];
    const float* rb1      = (const float*)d_in[10];
    const float* rW2      = (const float*)d_in[11];
    const float* l1s      = (const float*)d_in[12];
    const float* l1v      = (const float*)d_in[13];
    const float* l2s      = (const float*)d_in[14];
    const float* l2v      = (const float*)d_in[15];
    const float* scs      = (const float*)d_in[16];
    const float* scv      = (const float*)d_in[17];
    const float* sis      = (const float*)d_in[18];
    const float* siv      = (const float*)d_in[19];
    int n = in_sizes[0] / 6;
    int e = in_sizes[3];
    float* out = (float*)d_out;

    // ---- workspace carve ----
    float* w = (float*)d_ws;
    float* Q    = w; w += 128;
    float* yAs  = w; w += (size_t)n*64;
    float* yAv  = w; w += (size_t)n*192;
    float* yBs  = w; w += (size_t)n*64;
    float* yBv  = w; w += (size_t)n*192;
    float* aggS = w; w += (size_t)n*64;
    float* aggV = w; w += (size_t)n*192;
    float4* pos4 = (float4*)w; w += (size_t)n*4;
    uint2* mv    = (uint2*)w;  w += (size_t)n*128;   // n*64 uint2
    unsigned* Tsp = (unsigned*)w; w += (size_t)2*NATTR*32*128;
    unsigned* Tvp = (unsigned*)w; w += (size_t)2*NATTR*32*64;
    float2* radTab = (float2*)w; w += (size_t)2*(TBINS+1)*64*2;
    int* cnt       = (int*)w;
    int* offs      = cnt + n;
    int* cursor    = offs + (n + 1);
    int* srcSorted = cursor + n;
    size_t need = (size_t)((char*)(srcSorted + e) - (char*)d_ws);
    if (need > ws_size) {
        fprintf(stderr, "kernel_launch: ws too small (%zu > %zu)\n", need, ws_size);
        return;
    }

    const int AGG_GRID  = 1024;  // 4 blocks/CU (37.4 KB LDS)
    const int OC_GRID   = 1024;  // 4 blocks/CU (40 KB LDS)
    const int LIN_GRID  = 1024;

    kQ<<<1, 64, 0, stream>>>(upM, Q);
    hipMemsetAsync(cnt, 0, (size_t)n*sizeof(int), stream);
    kHist<<<(e + 255)/256, 256, 0, stream>>>(edst, cnt, e);
    kScan<<<1, 1024, 0, stream>>>(cnt, offs, cursor, n);
    kScatter<<<(e + 255)/256, 256, 0, stream>>>(esrc, edst, cursor, srcSorted, e);
    kT3<<<dim3(32, 2, 5), 256, 0, stream>>>(embT, scs, scv, Tsp, Tvp);
    kRadTab<<<dim3(TBINS+1, 2), 64, 0, stream>>>(rW1, rb1, rW2, radTab);
    kInitLin<<<1280, 256, 0, stream>>>(x, Q, l1v, yAs, yAv, pos4, mv, n);

    // ---- layer 0 (s1 == 0 analytically) ----
    kAgg<0><<<AGG_GRID, 256, 0, stream>>>(pos4, mv, offs, srcSorted,
                                  radTab, aggS, aggV, n);
    kOutComb<<<OC_GRID, 256, 0, stream>>>(yAs, yAv, yAs, yAv, aggS, aggV, nattr,
                                  l2s, l2v, Tsp, Tvp, sis, siv, Q, hArr, mArr, 0,
                                  yBs, yBv, pos4, out, 1, n);
    // ---- layer 1 ----
    kLin1<<<LIN_GRID, 256, 0, stream>>>(yBs, yBv, l1s + 4096, l1v + 4096, mv, n);
    kAgg<1><<<AGG_GRID, 256, 0, stream>>>(pos4, mv, offs, srcSorted,
                                  radTab + (size_t)(TBINS+1)*64, aggS, aggV, n);
    kOutComb<<<OC_GRID, 256, 0, stream>>>(yBs, yBv, yAs, yAv, aggS, aggV, nattr,
                                  l2s + (size_t)64*128, l2v + (size_t)64*64,
                                  Tsp + (size_t)NATTR*32*128, Tvp + (size_t)NATTR*32*64,
                                  sis + 4096, siv + 4096, Q, hArr, mArr, 1,
                                  yAs, yAv, pos4, out, 0, n);
}

// Round 7
// 575.006 us; speedup vs baseline: 2.5780x; 1.2204x over previous
//
#include <hip/hip_runtime.h>
#include <cstdio>
#include <cstdint>

#define CCH 64      // channels C
#define EMBD 32     // embedding dim
#define NBD 8       // num radial basis
#define RHD 32      // radial hidden
#define NATTR 100   // distinct node_attr values
#define TBINS 64    // radial table intervals (65 sample points)

static constexpr float MAXR    = 2.5f;
static constexpr float INVNN   = 0.17677669529663687f;  // 1/sqrt(32)
static constexpr float EFK     = 2.5298221281347035f;   // sqrt(2/2.5)*sqrt(8)
static constexpr float SQRT3   = 1.7320508075688772f;
static constexpr float PI_F    = 3.14159265358979323846f;

__device__ __forceinline__ float sigm_(float x) { return 1.f / (1.f + __expf(-x)); }
__device__ __forceinline__ float silu_(float x) { return x / (1.f + __expf(-x)); }
__device__ __forceinline__ unsigned f2bfu(float f) {   // RNE bf16 in low 16
    unsigned u = __float_as_uint(f);
    return (u + 0x7FFF + ((u >> 16) & 1)) >> 16;
}
__device__ __forceinline__ unsigned pack2(float lo, float hi) {
    return f2bfu(lo) | (f2bfu(hi) << 16);
}
__device__ __forceinline__ float ulo(unsigned u) { return __uint_as_float(u << 16); }
__device__ __forceinline__ float uhi(unsigned u) { return __uint_as_float(u & 0xFFFF0000u); }

// ---------------- Q = polar factor of uplift_M (64x2) ----------------
__global__ void kQ(const float* M, float* Q) {
    int c = threadIdx.x;  // 64 threads = 1 wave
    float m0 = M[2*c], m1 = M[2*c+1];
    float a = m0*m0, b = m0*m1, d = m1*m1;
    for (int o = 32; o > 0; o >>= 1) {
        a += __shfl_xor(a, o); b += __shfl_xor(b, o); d += __shfl_xor(d, o);
    }
    float det = a*d - b*b;
    float s = sqrtf(det);
    float t = sqrtf(a + d + 2.f*s);
    float inv = 1.f / (s*t);
    float i00 = (d + s)*inv, i01 = -b*inv, i11 = (a + s)*inv;
    Q[2*c]   = m0*i00 + m1*i01;
    Q[2*c+1] = m0*i01 + m1*i11;
}

// ---------------- radial table (bf16 pair): tab[l][bin][c] = pack(w1*coef, w2*coef) ----------------
__global__ void kRadTab(const float* __restrict__ rW1, const float* __restrict__ rb1,
                        const float* __restrict__ rW2, unsigned* __restrict__ tab) {
    int bin = blockIdx.x;       // 0..TBINS
    int l   = blockIdx.y;       // layer
    int lane = threadIdx.x;     // 64
    float r = bin * (MAXR / TBINS);
    float safe = fmaxf(r, 1e-9f);
    float invSafe = 1.f / safe;
    float th = PI_F * r * (1.f / MAXR);
    float s0, c0;
    __sincosf(th, &s0, &c0);
    __shared__ float hidS[RHD];
    if (lane < RHD) {
        float hs = rb1[l*RHD + lane];
        float sPrev = 0.f, sCur = s0, twoC = 2.f*c0;
        #pragma unroll
        for (int b = 0; b < NBD; ++b) {      // ef[b] = EFK*sin((b+1)th)*invSafe
            float efb = EFK * sCur * invSafe;
            hs = fmaf(efb, rW1[(l*NBD + b)*RHD + lane], hs);
            float sN = fmaf(twoC, sCur, -sPrev);
            sPrev = sCur; sCur = sN;
        }
        hidS[lane] = silu_(hs);
    }
    __syncthreads();
    float w1 = 0.f, w2 = 0.f;
    #pragma unroll
    for (int rr = 0; rr < RHD; ++rr) {
        float h = hidS[rr];
        w1 = fmaf(h, rW2[(l*RHD + rr)*128 + lane], w1);
        w2 = fmaf(h, rW2[(l*RHD + rr)*128 + 64 + lane], w2);
    }
    float cut = s0*s0;                       // == 0.5*(1-cos(pi*u))
    float coef = SQRT3 * cut * invSafe;
    tab[((size_t)l*(TBINS+1) + bin)*64 + lane] = pack2(w1*coef, w2*coef);
}

// ---------------- init: y0, pos4, layer-0 lin1 (s1=0; v1 = yv@L1v) ----------------
__global__ __launch_bounds__(256) void kInitLin(const float* __restrict__ x, const float* __restrict__ Qg,
        const float* __restrict__ L1v,
        float* __restrict__ yAs, float* __restrict__ yAv, float4* __restrict__ pos4,
        uint2* __restrict__ mv, int n) {
    __shared__ unsigned wPk[32*64];   // pack(L1v[c][o], L1v[c+1][o]) : 8 KB
    __shared__ uint2 bc[4][64];
    int t = threadIdx.x;
    for (int i = t; i < 32*64; i += 256) {
        int cp = i >> 6, o = i & 63;
        wPk[i] = pack2(L1v[(2*cp)*64 + o], L1v[(2*cp+1)*64 + o]);
    }
    __syncthreads();
    int lane = t & 63;
    int wid = t >> 6;
    float q0 = Qg[2*lane], q1 = Qg[2*lane+1];
    for (int node = blockIdx.x*4 + wid; node < n; node += gridDim.x*4) {
        const float* xr = x + (size_t)node*6;
        float x0 = xr[0], x1 = xr[1], x2 = xr[2], x3 = xr[3], x4 = xr[4], x5 = xr[5];
        float y0 = q0*x0 + q1*x3;
        float y1 = q0*x1 + q1*x4;
        float y2 = q0*x2 + q1*x5;
        float* yv = yAv + (size_t)node*192 + lane*3;
        yv[0] = y0; yv[1] = y1; yv[2] = y2;
        yAs[(size_t)node*64 + lane] = 0.f;
        if (lane == 0) pos4[node] = (float4){x0, x1, x2, 0.f};
        bc[wid][lane] = (uint2){ pack2(y0, y1), pack2(y2, 0.f) };
        float a0A=0.f, a0B=0.f, a1A=0.f, a1B=0.f, a2A=0.f, a2B=0.f;
        #pragma unroll 8
        for (int cp = 0; cp < 32; ++cp) {
            int c = 2*cp;
            uint2 b0 = bc[wid][c];
            uint2 b1 = bc[wid][c+1];
            unsigned wp = wPk[cp*64 + lane];
            float wv0 = ulo(wp), wv1 = uhi(wp);
            a0A = fmaf(ulo(b0.x), wv0, a0A); a0B = fmaf(ulo(b1.x), wv1, a0B);
            a1A = fmaf(uhi(b0.x), wv0, a1A); a1B = fmaf(uhi(b1.x), wv1, a1B);
            a2A = fmaf(ulo(b0.y), wv0, a2A); a2B = fmaf(ulo(b1.y), wv1, a2B);
        }
        mv[(size_t)node*64 + lane] =
            (uint2){ pack2(a0A+a0B, a1A+a1B), pack2(a2A+a2B, 0.f) };
    }
}

// ---------------- CSR build ----------------
__global__ void kHist(const int* dst, int* cnt, int e) {
    int i = blockIdx.x*blockDim.x + threadIdx.x;
    if (i < e) atomicAdd(&cnt[dst[i]], 1);
}

__global__ void kScan(const int* cnt, int* offs, int* cursor, int n) {
    __shared__ int part[1024];
    int t = threadIdx.x;
    int chunk = (n + 1023) >> 10;
    int lo = t*chunk, hi = min(lo + chunk, n);
    int s = 0;
    for (int i = lo; i < hi; ++i) s += cnt[i];
    part[t] = s;
    __syncthreads();
    for (int o = 1; o < 1024; o <<= 1) {
        int w = (t >= o) ? part[t - o] : 0;
        __syncthreads();
        part[t] += w;
        __syncthreads();
    }
    int run = part[t] - s;
    for (int i = lo; i < hi; ++i) {
        int cv = cnt[i];
        offs[i] = run; cursor[i] = run;
        run += cv;
    }
    if (t == 1023) offs[n] = part[1023];
}

__global__ void kScatter(const int* src, const int* dst, int* cursor,
                         int* srcSorted, int e) {
    int i = blockIdx.x*blockDim.x + threadIdx.x;
    if (i < e) {
        int p = atomicAdd(&cursor[dst[i]], 1);
        srcSorted[p] = src[i];
    }
}

// ---------------- T tables: bf16 c-pair packed ----------------
__global__ __launch_bounds__(256) void kT3(const float* __restrict__ embT,
        const float* __restrict__ scs, const float* __restrict__ scv,
        unsigned* __restrict__ Tsp, unsigned* __restrict__ Tvp) {
    int cp = blockIdx.x, l = blockIdx.y, ag = blockIdx.z;  // 32 x 2 x 5
    int c0 = 2*cp, c1 = c0 + 1;
    __shared__ float sS0[32*128], sS1[32*128], sV0[32*64], sV1[32*64], sE[20*EMBD];
    int t = threadIdx.x;
    const float* p0 = scs + ((size_t)(l*CCH + c0)*EMBD)*128;
    const float* p1 = scs + ((size_t)(l*CCH + c1)*EMBD)*128;
    for (int i = t; i < 32*128; i += 256) { sS0[i] = p0[i]; sS1[i] = p1[i]; }
    const float* q0 = scv + ((size_t)(l*CCH + c0)*EMBD)*64;
    const float* q1 = scv + ((size_t)(l*CCH + c1)*EMBD)*64;
    for (int i = t; i < 32*64; i += 256) { sV0[i] = q0[i]; sV1[i] = q1[i]; }
    const float* eb = embT + (size_t)ag*20*EMBD;
    for (int i = t; i < 20*EMBD; i += 256) sE[i] = eb[i];
    __syncthreads();
    if (t < 128) {
        int o = t;
        for (int a = 0; a < 20; ++a) {
            float acc0 = 0.f, acc1 = 0.f;
            #pragma unroll
            for (int e = 0; e < EMBD; ++e) {
                float ev = sE[a*EMBD + e];
                acc0 = fmaf(ev, sS0[e*128 + o], acc0);
                acc1 = fmaf(ev, sS1[e*128 + o], acc1);
            }
            int aa = ag*20 + a;
            Tsp[(((size_t)l*NATTR + aa)*32 + cp)*128 + o] = pack2(acc0, acc1);
        }
    } else if (t < 192) {
        int o = t - 128;
        for (int a = 0; a < 20; ++a) {
            float acc0 = 0.f, acc1 = 0.f;
            #pragma unroll
            for (int e = 0; e < EMBD; ++e) {
                float ev = sE[a*EMBD + e];
                acc0 = fmaf(ev, sV0[e*64 + o], acc0);
                acc1 = fmaf(ev, sV1[e*64 + o], acc1);
            }
            int aa = ag*20 + a;
            Tvp[(((size_t)l*NATTR + aa)*32 + cp)*64 + o] = pack2(acc0, acc1);
        }
    }
}

// ---------------- lin1 (layer 1): s1,v1 -> packed bf16 mv; LDS-broadcast, packed weights ----------------
__global__ __launch_bounds__(256) void kLin1(const float* __restrict__ ys, const float* __restrict__ yv,
        const float* __restrict__ L1s, const float* __restrict__ L1v,
        uint2* __restrict__ mv, int n) {
    __shared__ uint2 wPk[32*64];   // {pk(L1s c,c+1), pk(L1v c,c+1)} : 16 KB
    __shared__ uint2 bc[4][64];
    int t = threadIdx.x;
    for (int i = t; i < 32*64; i += 256) {
        int cp = i >> 6, o = i & 63;
        wPk[i] = (uint2){ pack2(L1s[(2*cp)*64 + o], L1s[(2*cp+1)*64 + o]),
                          pack2(L1v[(2*cp)*64 + o], L1v[(2*cp+1)*64 + o]) };
    }
    __syncthreads();
    int lane = t & 63;
    int wid = t >> 6;
    for (int node = blockIdx.x*4 + wid; node < n; node += gridDim.x*4) {
        float ys_r = ys[(size_t)node*64 + lane];
        const float* yvp = yv + (size_t)node*192 + lane*3;
        float y0 = yvp[0], y1 = yvp[1], y2 = yvp[2];
        bc[wid][lane] = (uint2){ pack2(y0, y1), pack2(y2, ys_r) };
        float asA=0.f, asB=0.f, a0A=0.f, a0B=0.f, a1A=0.f, a1B=0.f, a2A=0.f, a2B=0.f;
        #pragma unroll 8
        for (int cp = 0; cp < 32; ++cp) {
            int c = 2*cp;
            uint2 b0 = bc[wid][c];
            uint2 b1 = bc[wid][c+1];
            uint2 wp = wPk[cp*64 + lane];
            float ws0 = ulo(wp.x), ws1 = uhi(wp.x);
            float wv0 = ulo(wp.y), wv1 = uhi(wp.y);
            asA = fmaf(uhi(b0.y), ws0, asA); asB = fmaf(uhi(b1.y), ws1, asB);
            a0A = fmaf(ulo(b0.x), wv0, a0A); a0B = fmaf(ulo(b1.x), wv1, a0B);
            a1A = fmaf(uhi(b0.x), wv0, a1A); a1B = fmaf(uhi(b1.x), wv1, a1B);
            a2A = fmaf(ulo(b0.y), wv0, a2A); a2B = fmaf(ulo(b1.y), wv1, a2B);
        }
        mv[(size_t)node*64 + lane] =
            (uint2){ pack2(a0A+a0B, a1A+a1B), pack2(a2A+a2B, asA+asB) };
    }
}

// ---------------- aggregation: bf16 table lerp, 7 blocks/CU ----------------
template<int WITHV>
__global__ __launch_bounds__(256) void kAgg(const float4* __restrict__ pos4,
        const uint2* __restrict__ mv,
        const int* __restrict__ offs, const int* __restrict__ srcSorted,
        const unsigned* __restrict__ tabG,
        float* __restrict__ aggS, float* __restrict__ aggV, int n) {
    __shared__ unsigned tab[(TBINS+1)*64];   // 16.6 KB bf16 pairs
    __shared__ float red[4][64][4];
    int t = threadIdx.x;
    for (int i = t; i < (TBINS+1)*64; i += 256) tab[i] = tabG[i];
    __syncthreads();
    int lane = t & 63;
    int wid = t >> 6;

    for (int node = blockIdx.x; node < n; node += gridDim.x) {
        float4 pc = pos4[node];
        float px = pc.x, py = pc.y, pz = pc.z;
        int beg = offs[node], end = offs[node+1];
        float accS = 0.f, av0 = 0.f, av1 = 0.f, av2 = 0.f;
        int idx = beg + wid;
        int srcA = 0, srcB = 0;
        float4 pA = (float4){0.f,0.f,0.f,0.f};
        if (idx < end) srcA = srcSorted[idx];
        if (idx + 4 < end) srcB = srcSorted[idx + 4];
        if (idx < end) pA = pos4[srcA];
        for (; idx < end; idx += 4) {
            int srcU = srcA;
            float ex = pA.x - px, ey = pA.y - py, ez = pA.z - pz;
            srcA = srcB;
            if (idx + 8 < end) srcB = srcSorted[idx + 8];
            if (idx + 4 < end) pA = pos4[srcA];
            float el2 = ex*ex + ey*ey + ez*ez;
            if (el2 >= MAXR*MAXR) continue;   // wave-uniform: cut == 0
            uint2 mw = mv[(size_t)srcU*64 + lane];   // {v1x,v1y | v1z,s1} bf16
            float elen = sqrtf(el2);
            float u = elen * ((float)TBINS / MAXR);  // < TBINS
            int i0 = (int)u;
            float fr = u - (float)i0;
            unsigned t0 = tab[i0*64 + lane];
            unsigned t1 = tab[i0*64 + 64 + lane];
            float w1 = fmaf(fr, ulo(t1) - ulo(t0), ulo(t0));  // w1 * sqrt3*cut/safe
            float w2 = fmaf(fr, uhi(t1) - uhi(t0), uhi(t0));  // w2 * sqrt3*cut/safe
            float vv0 = ulo(mw.x), vv1 = uhi(mw.x), vv2 = ulo(mw.y);
            float dv = vv0*ex + vv1*ey + vv2*ez;
            accS = fmaf(w2, dv, accS);
            if (WITHV) {
                float tt = w1 * uhi(mw.y);
                av0 = fmaf(tt, ex, av0); av1 = fmaf(tt, ey, av1); av2 = fmaf(tt, ez, av2);
            }
        }
        red[wid][lane][0] = accS; red[wid][lane][1] = av0;
        red[wid][lane][2] = av1;  red[wid][lane][3] = av2;
        __syncthreads();
        if (wid == 0) {
            float rs = red[0][lane][0] + red[1][lane][0] + red[2][lane][0] + red[3][lane][0];
            aggS[(size_t)node*64 + lane] = rs*INVNN;
            float r0 = red[0][lane][1] + red[1][lane][1] + red[2][lane][1] + red[3][lane][1];
            float r1 = red[0][lane][2] + red[1][lane][2] + red[2][lane][2] + red[3][lane][2];
            float r2 = red[0][lane][3] + red[1][lane][3] + red[2][lane][3] + red[3][lane][3];
            float* ap = aggV + (size_t)node*192 + lane*3;
            ap[0] = r0*INVNN; ap[1] = r1*INVNN; ap[2] = r2*INVNN;
        }
        __syncthreads();
    }
}

// ---------------- fused out+gating+combine: LDS-broadcast rows, packed weight reads ----------------
__global__ __launch_bounds__(256) void kOutComb(const float* __restrict__ ys, const float* __restrict__ yv,
        const float* __restrict__ yolds, const float* __restrict__ yoldv,
        const float* __restrict__ aggS, const float* __restrict__ aggV, const int* __restrict__ attr,
        const float* __restrict__ L2s, const float* __restrict__ L2v,
        const unsigned* __restrict__ Tsp, const unsigned* __restrict__ Tvp,
        const float* __restrict__ siS, const float* __restrict__ siV, const float* __restrict__ Qg,
        const float* __restrict__ hArr, const float* __restrict__ mArr, int li,
        float* __restrict__ newS, float* __restrict__ newV,
        float4* __restrict__ pos4out, float* __restrict__ xout6,
        int writeY, int n) {
    __shared__ uint2 wAB[32*64];     // {pk(L2s[c..c+1][o]), pk(L2s[c..c+1][64+o])} : 16 KB
    __shared__ uint2 wLS[32*64];     // {pk(L2v), pk(siS)} : 16 KB
    __shared__ unsigned wSv[32*64];  // pk(siV) : 8 KB
    __shared__ uint4 bcast[4][64];   // 4 KB
    int t = threadIdx.x;
    for (int i = t; i < 32*64; i += 256) {
        int cp = i >> 6, o = i & 63;
        wAB[i] = (uint2){ pack2(L2s[(2*cp)*128 + o],      L2s[(2*cp+1)*128 + o]),
                          pack2(L2s[(2*cp)*128 + 64 + o], L2s[(2*cp+1)*128 + 64 + o]) };
        wLS[i] = (uint2){ pack2(L2v[(2*cp)*64 + o], L2v[(2*cp+1)*64 + o]),
                          pack2(siS[(2*cp)*64 + o], siS[(2*cp+1)*64 + o]) };
        wSv[i] = pack2(siV[(2*cp)*64 + o], siV[(2*cp+1)*64 + o]);
    }
    __syncthreads();
    int lane = t & 63;
    int wid = t >> 6;
    float hh = hArr[li]; hh *= hh;
    float m = mArr[li];
    float q0 = Qg[2*lane], q1 = Qg[2*lane+1];
    for (int node = blockIdx.x*4 + wid; node < n; node += gridDim.x*4) {
        int a = attr[node];
        const unsigned* tS = Tsp + (size_t)a*32*128;
        const unsigned* tV = Tvp + (size_t)a*32*64;
        float as_r = aggS[(size_t)node*64 + lane];
        float ys_r = ys[(size_t)node*64 + lane];
        const float* avp = aggV + (size_t)node*192 + lane*3;
        float av0 = avp[0], av1 = avp[1], av2 = avp[2];
        const float* yvp = yv + (size_t)node*192 + lane*3;
        float by0 = yvp[0], by1 = yvp[1], by2 = yvp[2];
        // stage this node's per-channel row (bf16 packs); per-wave slot, no barrier
        bcast[wid][lane] = (uint4){ pack2(as_r, ys_r), pack2(av0, by0),
                                    pack2(av1, by1),   pack2(av2, by2) };
        float oS0A=0.f,oS0B=0.f, oS1A=0.f,oS1B=0.f;
        float ov0A=0.f,ov0B=0.f, ov1A=0.f,ov1B=0.f, ov2A=0.f,ov2B=0.f;
        float q2sA=0.f,q2sB=0.f, qv0A=0.f,qv0B=0.f, qv1A=0.f,qv1B=0.f, qv2A=0.f,qv2B=0.f;
        #pragma unroll 4
        for (int cp = 0; cp < 32; ++cp) {
            int c = 2*cp;
            uint4 b0 = bcast[wid][c];       // wave-uniform addr -> broadcast
            uint4 b1 = bcast[wid][c+1];
            float asc0 = ulo(b0.x), ysc0 = uhi(b0.x);
            float asc1 = ulo(b1.x), ysc1 = uhi(b1.x);
            float a00 = ulo(b0.y), b00 = uhi(b0.y);
            float a10 = ulo(b1.y), b10 = uhi(b1.y);
            float a01 = ulo(b0.z), b01 = uhi(b0.z);
            float a11 = ulo(b1.z), b11 = uhi(b1.z);
            float a02 = ulo(b0.w), b02 = uhi(b0.w);
            float a12 = ulo(b1.w), b12 = uhi(b1.w);
            uint2 ab = wAB[cp*64 + lane];
            uint2 ls = wLS[cp*64 + lane];
            unsigned sv = wSv[cp*64 + lane];
            unsigned ts0 = tS[cp*128 + lane];
            unsigned ts1 = tS[cp*128 + 64 + lane];
            unsigned tvw = tV[cp*64 + lane];
            float lsa0 = ulo(ab.x), lsa1 = uhi(ab.x);
            float lsb0 = ulo(ab.y), lsb1 = uhi(ab.y);
            float lv0 = ulo(ls.x), lv1 = uhi(ls.x);
            float ws0 = ulo(ls.y), ws1 = uhi(ls.y);
            float wv0 = ulo(sv), wv1 = uhi(sv);
            float tsa0 = ulo(ts0), tsa1 = uhi(ts0);
            float tsb0 = ulo(ts1), tsb1 = uhi(ts1);
            float tv0 = ulo(tvw), tv1 = uhi(tvw);
            oS0A = fmaf(asc0, lsa0, fmaf(ysc0, tsa0, oS0A));
            oS0B = fmaf(asc1, lsa1, fmaf(ysc1, tsa1, oS0B));
            oS1A = fmaf(asc0, lsb0, fmaf(ysc0, tsb0, oS1A));
            oS1B = fmaf(asc1, lsb1, fmaf(ysc1, tsb1, oS1B));
            ov0A = fmaf(a00, lv0, fmaf(b00, tv0, ov0A));
            ov0B = fmaf(a10, lv1, fmaf(b10, tv1, ov0B));
            ov1A = fmaf(a01, lv0, fmaf(b01, tv0, ov1A));
            ov1B = fmaf(a11, lv1, fmaf(b11, tv1, ov1B));
            ov2A = fmaf(a02, lv0, fmaf(b02, tv0, ov2A));
            ov2B = fmaf(a12, lv1, fmaf(b12, tv1, ov2B));
            q2sA = fmaf(ysc0, ws0, q2sA); q2sB = fmaf(ysc1, ws1, q2sB);
            qv0A = fmaf(b00, wv0, qv0A);  qv0B = fmaf(b10, wv1, qv0B);
            qv1A = fmaf(b01, wv0, qv1A);  qv1B = fmaf(b11, wv1, qv1B);
            qv2A = fmaf(b02, wv0, qv2A);  qv2B = fmaf(b12, wv1, qv2B);
        }
        float gs = silu_(oS0A + oS0B);
        float sg = sigm_(oS1A + oS1B);
        float gv0 = sg*(ov0A+ov0B), gv1 = sg*(ov1A+ov1B), gv2 = sg*(ov2A+ov2B);
        float q2s = q2sA+q2sB, qv0 = qv0A+qv0B, qv1 = qv1A+qv1B, qv2 = qv2A+qv2B;
        float yos = yolds[(size_t)node*64 + lane];
        const float* yop = yoldv + (size_t)node*192 + lane*3;
        float ns  = 2.f*ys_r - yos   + hh*(m*gs  + (m-1.f)*q2s);
        float nv0 = 2.f*by0 - yop[0] + hh*(m*gv0 + (m-1.f)*qv0);
        float nv1 = 2.f*by1 - yop[1] + hh*(m*gv1 + (m-1.f)*qv1);
        float nv2 = 2.f*by2 - yop[2] + hh*(m*gv2 + (m-1.f)*qv2);
        if (writeY) {
            newS[(size_t)node*64 + lane] = ns;
            float* np = newV + (size_t)node*192 + lane*3;
            np[0] = nv0; np[1] = nv1; np[2] = nv2;
        }
        float p00 = nv0*q0, p01 = nv1*q0, p02 = nv2*q0;
        float p10 = nv0*q1, p11 = nv1*q1, p12 = nv2*q1;
        for (int o = 32; o > 0; o >>= 1) {
            p00 += __shfl_xor(p00, o); p01 += __shfl_xor(p01, o); p02 += __shfl_xor(p02, o);
            p10 += __shfl_xor(p10, o); p11 += __shfl_xor(p11, o); p12 += __shfl_xor(p12, o);
        }
        if (lane == 0) {
            if (writeY) {
                pos4out[node] = (float4){p00, p01, p02, 0.f};
            } else {
                float* xp = xout6 + (size_t)node*6;
                xp[0] = p00; xp[1] = p01; xp[2] = p02;
                xp[3] = p10; xp[4] = p11; xp[5] = p12;
            }
        }
    }
}

extern "C" void kernel_launch(void* const* d_in, const int* in_sizes, int n_in,
                              void* d_out, int out_size, void* d_ws, size_t ws_size,
                              hipStream_t stream) {
    const float* x        = (const float*)d_in[0];
    const int*   nattr    = (const int*)  d_in[2];
    const int*   esrc     = (const int*)  d_in[3];
    const int*   edst     = (const int*)  d_in[4];
    const float* embT     = (const float*)d_in[5];
    const float* upM      = (const float*)d_in[6];
    const float* hArr     = (const float*)d_in[7];
    const float* mArr     = (const float*)d_in[8];
    const float* rW1      = (const float*)d_in[9];
    const float* rb1      = (const float*)d_in[10];
    const float* rW2      = (const float*)d_in[11];
    const float* l1s      = (const float*)d_in[12];
    const float* l1v      = (const float*)d_in[13];
    const float* l2s      = (const float*)d_in[14];
    const float* l2v      = (const float*)d_in[15];
    const float* scs      = (const float*)d_in[16];
    const float* scv      = (const float*)d_in[17];
    const float* sis      = (const float*)d_in[18];
    const float* siv      = (const float*)d_in[19];
    int n = in_sizes[0] / 6;
    int e = in_sizes[3];
    float* out = (float*)d_out;

    // ---- workspace carve ----
    float* w = (float*)d_ws;
    float* Q    = w; w += 128;
    float* yAs  = w; w += (size_t)n*64;
    float* yAv  = w; w += (size_t)n*192;
    float* yBs  = w; w += (size_t)n*64;
    float* yBv  = w; w += (size_t)n*192;
    float* aggS = w; w += (size_t)n*64;
    float* aggV = w; w += (size_t)n*192;
    float4* pos4 = (float4*)w; w += (size_t)n*4;
    uint2* mv    = (uint2*)w;  w += (size_t)n*128;   // n*64 uint2
    unsigned* Tsp = (unsigned*)w; w += (size_t)2*NATTR*32*128;
    unsigned* Tvp = (unsigned*)w; w += (size_t)2*NATTR*32*64;
    unsigned* radTab = (unsigned*)w; w += (size_t)2*(TBINS+1)*64;
    int* cnt       = (int*)w;
    int* offs      = cnt + n;
    int* cursor    = offs + (n + 1);
    int* srcSorted = cursor + n;
    size_t need = (size_t)((char*)(srcSorted + e) - (char*)d_ws);
    if (need > ws_size) {
        fprintf(stderr, "kernel_launch: ws too small (%zu > %zu)\n", need, ws_size);
        return;
    }

    const int AGG_GRID  = 1792;  // 7 blocks/CU (20.7 KB LDS)
    const int OC_GRID   = 768;   // 3 blocks/CU (44 KB LDS)
    const int LIN_GRID  = 2048;

    kQ<<<1, 64, 0, stream>>>(upM, Q);
    hipMemsetAsync(cnt, 0, (size_t)n*sizeof(int), stream);
    kHist<<<(e + 255)/256, 256, 0, stream>>>(edst, cnt, e);
    kScan<<<1, 1024, 0, stream>>>(cnt, offs, cursor, n);
    kScatter<<<(e + 255)/256, 256, 0, stream>>>(esrc, edst, cursor, srcSorted, e);
    kT3<<<dim3(32, 2, 5), 256, 0, stream>>>(embT, scs, scv, Tsp, Tvp);
    kRadTab<<<dim3(TBINS+1, 2), 64, 0, stream>>>(rW1, rb1, rW2, radTab);
    kInitLin<<<LIN_GRID, 256, 0, stream>>>(x, Q, l1v, yAs, yAv, pos4, mv, n);

    // ---- layer 0 (s1 == 0 analytically) ----
    kAgg<0><<<AGG_GRID, 256, 0, stream>>>(pos4, mv, offs, srcSorted,
                                  radTab, aggS, aggV, n);
    kOutComb<<<OC_GRID, 256, 0, stream>>>(yAs, yAv, yAs, yAv, aggS, aggV, nattr,
                                  l2s, l2v, Tsp, Tvp, sis, siv, Q, hArr, mArr, 0,
                                  yBs, yBv, pos4, out, 1, n);
    // ---- layer 1 ----
    kLin1<<<LIN_GRID, 256, 0, stream>>>(yBs, yBv, l1s + 4096, l1v + 4096, mv, n);
    kAgg<1><<<AGG_GRID, 256, 0, stream>>>(pos4, mv, offs, srcSorted,
                                  radTab + (size_t)(TBINS+1)*64, aggS, aggV, n);
    kOutComb<<<OC_GRID, 256, 0, stream>>>(yBs, yBv, yAs, yAv, aggS, aggV, nattr,
                                  l2s + (size_t)64*128, l2v + (size_t)64*64,
                                  Tsp + (size_t)NATTR*32*128, Tvp + (size_t)NATTR*32*64,
                                  sis + 4096, siv + 4096, Q, hArr, mArr, 1,
                                  yAs, yAv, pos4, out, 0, n);
}